// Round 1
// baseline (11320.112 us; speedup 1.0000x reference)
//
#include <hip/hip_runtime.h>
#include <hip/hip_bf16.h>

// ---------------------------------------------------------------------------
// GCN (3-layer) + encoder + rank_diff stats, all fp32.
//   h = x @ encW.T + encb            -> stat0
//   h = relu(conv(h,W0,b0))          -> stat1
//   h = relu(conv(h,W1,b1))          -> stat2
//   h = conv(h,W2,b2)                -> stat3, h is output 0
// conv(h) = segsum(h@W.T [src] * dinv[src]*dinv[dst], dst) + b
// rank_diff via Gram matrices: stat = trace(sqrt(G')) with G' closed form.
// Eigensolve: register-resident Householder tridiag + multisection Sturm.
// ---------------------------------------------------------------------------

#define DIM 128

// ------------------------------- graph setup -------------------------------

__global__ void k_deg(const int* __restrict__ dst, unsigned* __restrict__ deg, int E) {
  int e = blockIdx.x * 256 + threadIdx.x;
  if (e < E) atomicAdd(&deg[dst[e]], 1u);
}

__global__ __launch_bounds__(1024) void k_scan(const unsigned* __restrict__ deg,
                                               unsigned* __restrict__ rowptr, int n) {
  __shared__ unsigned wtot[17];
  __shared__ unsigned sh_run;
  int tid = threadIdx.x;
  int lane = tid & 63, wid = tid >> 6;
  if (tid == 0) sh_run = 0;
  __syncthreads();
  for (int base = 0; base < n; base += 1024) {
    int i = base + tid;
    unsigned v = (i < n) ? deg[i] : 0u;
    unsigned s = v;
    #pragma unroll
    for (int d = 1; d < 64; d <<= 1) {
      unsigned t = __shfl_up(s, d);
      if (lane >= d) s += t;
    }
    if (lane == 63) wtot[wid] = s;
    __syncthreads();
    if (tid == 0) {
      unsigned acc = 0;
      #pragma unroll
      for (int w = 0; w < 16; w++) { unsigned t = wtot[w]; wtot[w] = acc; acc += t; }
      wtot[16] = acc;
    }
    __syncthreads();
    if (i < n) rowptr[i] = sh_run + wtot[wid] + (s - v);
    __syncthreads();
    if (tid == 0) sh_run += wtot[16];
    __syncthreads();
  }
  if (tid == 0) rowptr[n] = sh_run;
}

__global__ void k_dinv(const unsigned* __restrict__ deg, float* __restrict__ dinv,
                       const unsigned* __restrict__ rowptr, unsigned* __restrict__ cursor, int N) {
  int i = blockIdx.x * 256 + threadIdx.x;
  if (i < N) {
    unsigned d = deg[i];
    dinv[i] = d ? 1.0f / sqrtf((float)d) : 0.0f;
    cursor[i] = rowptr[i];
  }
}

__global__ void k_scatter(const int* __restrict__ src, const int* __restrict__ dst,
                          const float* __restrict__ dinv, unsigned* __restrict__ cursor,
                          int* __restrict__ srcs, float* __restrict__ nrm, int E) {
  int e = blockIdx.x * 256 + threadIdx.x;
  if (e >= E) return;
  int s = src[e], d = dst[e];
  unsigned pos = atomicAdd(&cursor[d], 1u);
  srcs[pos] = s;
  nrm[pos] = dinv[s] * dinv[d];
}

// ------------------------------- GEMM: out = A @ W.T (+bias) ----------------
// A: M x 128, W: 128 x 128 (row-major, out_dim x in_dim), out: M x 128

__global__ __launch_bounds__(256) void k_gemm(const float* __restrict__ A,
                                              const float* __restrict__ W,
                                              const float* __restrict__ bias,
                                              float* __restrict__ out, int M) {
  __shared__ float Hs[32][68];    // k-major: Hs[kk][row]
  __shared__ float Ws[32][132];   // k-major: Ws[kk][col]
  int tid = threadIdx.x;
  int r0 = blockIdx.x * 64;
  int tx = tid & 15, ty = tid >> 4;
  float acc[4][8];
  #pragma unroll
  for (int i = 0; i < 4; i++)
    #pragma unroll
    for (int j = 0; j < 8; j++) acc[i][j] = 0.f;

  #pragma unroll
  for (int k0 = 0; k0 < 128; k0 += 32) {
    // load H tile (64 rows x 32 k) transposed into LDS
    {
      int r = tid >> 2, sb = tid & 3;
      #pragma unroll
      for (int s2 = 0; s2 < 2; s2++) {
        int s = sb + 4 * s2;
        float4 v = make_float4(0.f, 0.f, 0.f, 0.f);
        int gr = r0 + r;
        if (gr < M) v = *(const float4*)&A[(size_t)gr * 128 + k0 + 4 * s];
        Hs[4 * s + 0][r] = v.x; Hs[4 * s + 1][r] = v.y;
        Hs[4 * s + 2][r] = v.z; Hs[4 * s + 3][r] = v.w;
      }
    }
    // load W tile (128 cols x 32 k) transposed into LDS
    {
      int c = tid >> 1, hb = (tid & 1) * 4;
      #pragma unroll
      for (int s2 = 0; s2 < 4; s2++) {
        int s = hb + s2;
        float4 v = *(const float4*)&W[(size_t)c * 128 + k0 + 4 * s];
        Ws[4 * s + 0][c] = v.x; Ws[4 * s + 1][c] = v.y;
        Ws[4 * s + 2][c] = v.z; Ws[4 * s + 3][c] = v.w;
      }
    }
    __syncthreads();
    #pragma unroll
    for (int kk = 0; kk < 32; kk++) {
      float4 rh = *(const float4*)&Hs[kk][ty * 4];
      float4 rw0 = *(const float4*)&Ws[kk][tx * 8];
      float4 rw1 = *(const float4*)&Ws[kk][tx * 8 + 4];
      float a[4] = { rh.x, rh.y, rh.z, rh.w };
      float b[8] = { rw0.x, rw0.y, rw0.z, rw0.w, rw1.x, rw1.y, rw1.z, rw1.w };
      #pragma unroll
      for (int i = 0; i < 4; i++)
        #pragma unroll
        for (int j = 0; j < 8; j++) acc[i][j] += a[i] * b[j];
    }
    __syncthreads();
  }
  float bb[8] = {0.f,0.f,0.f,0.f,0.f,0.f,0.f,0.f};
  if (bias) {
    float4 b0 = *(const float4*)&bias[tx * 8];
    float4 b1 = *(const float4*)&bias[tx * 8 + 4];
    bb[0]=b0.x; bb[1]=b0.y; bb[2]=b0.z; bb[3]=b0.w;
    bb[4]=b1.x; bb[5]=b1.y; bb[6]=b1.z; bb[7]=b1.w;
  }
  #pragma unroll
  for (int i = 0; i < 4; i++) {
    int gr = r0 + ty * 4 + i;
    if (gr < M) {
      float4 o0 = make_float4(acc[i][0]+bb[0], acc[i][1]+bb[1], acc[i][2]+bb[2], acc[i][3]+bb[3]);
      float4 o1 = make_float4(acc[i][4]+bb[4], acc[i][5]+bb[5], acc[i][6]+bb[6], acc[i][7]+bb[7]);
      *(float4*)&out[(size_t)gr * 128 + tx * 8] = o0;
      *(float4*)&out[(size_t)gr * 128 + tx * 8 + 4] = o1;
    }
  }
}

// ------------------------------- aggregation -------------------------------
// out[n] = sum_e nrm[e]*tmp[srcs[e]] + bias ; optional relu. wave per node.

template <bool RELU>
__global__ __launch_bounds__(256) void k_agg(const float* __restrict__ tmp,
                                             const unsigned* __restrict__ rowptr,
                                             const int* __restrict__ srcs,
                                             const float* __restrict__ nrm,
                                             const float* __restrict__ bias,
                                             float* __restrict__ out, int N) {
  int wid = threadIdx.x >> 6, lane = threadIdx.x & 63;
  int n = blockIdx.x * 4 + wid;
  if (n >= N) return;
  unsigned e0 = rowptr[n], e1 = rowptr[n + 1];
  float a0 = 0.f, a1 = 0.f;
  for (unsigned e = e0; e < e1; e++) {
    int s = srcs[e];
    float w = nrm[e];
    a0 += w * tmp[(size_t)s * 128 + lane];
    a1 += w * tmp[(size_t)s * 128 + 64 + lane];
  }
  a0 += bias[lane];
  a1 += bias[64 + lane];
  if (RELU) { a0 = fmaxf(a0, 0.f); a1 = fmaxf(a1, 0.f); }
  out[(size_t)n * 128 + lane] = a0;
  out[(size_t)n * 128 + 64 + lane] = a1;
}

// ------------------------------- row/col stats -----------------------------

__global__ __launch_bounds__(256) void k_rowstats(const float* __restrict__ h,
                                                  float* __restrict__ colsum,
                                                  unsigned long long* __restrict__ packed,
                                                  int N) {
  __shared__ float cs[4][128];
  int tid = threadIdx.x, wid = tid >> 6, lane = tid & 63;
  int n = blockIdx.x * 4 + wid;
  float a0 = 0.f, a1 = 0.f;
  if (n < N) {
    a0 = fabsf(h[(size_t)n * 128 + lane]);
    a1 = fabsf(h[(size_t)n * 128 + 64 + lane]);
  }
  cs[wid][lane] = a0;
  cs[wid][64 + lane] = a1;
  float rs = a0 + a1;
  #pragma unroll
  for (int m = 32; m >= 1; m >>= 1) rs += __shfl_xor(rs, m);
  if (lane == 0 && n < N) {
    unsigned long long pk =
        ((unsigned long long)__float_as_uint(rs) << 32) |
        (unsigned long long)(0xFFFFFFFFu - (unsigned)n);
    atomicMax(packed, pk);
  }
  __syncthreads();
  if (tid < 128) {
    float s = cs[0][tid] + cs[1][tid] + cs[2][tid] + cs[3][tid];
    atomicAdd(&colsum[tid], s);
  }
}

__global__ void k_extract(const float* __restrict__ h,
                          const unsigned long long* __restrict__ packed,
                          float* __restrict__ hrow, int N) {
  unsigned long long pk = *packed;
  unsigned i = 0xFFFFFFFFu - (unsigned)(pk & 0xFFFFFFFFull);
  if (i >= (unsigned)N) i = 0;
  hrow[threadIdx.x] = h[(size_t)i * 128 + threadIdx.x];
}

// ------------------------------- SYRK: G += h^T h --------------------------

__global__ __launch_bounds__(256) void k_syrk(const float* __restrict__ h,
                                              float* __restrict__ G, int N, int rowsPer) {
  __shared__ float hs[8][132];
  int tid = threadIdx.x;
  int tx = tid & 15, ty = tid >> 4;
  float acc[8][8];
  #pragma unroll
  for (int i = 0; i < 8; i++)
    #pragma unroll
    for (int j = 0; j < 8; j++) acc[i][j] = 0.f;

  int rstart = blockIdx.x * rowsPer;
  int rend = rstart + rowsPer;
  if (rend > N) rend = N;
  for (int rb = rstart; rb < rend; rb += 8) {
    int rr = tid >> 5;
    int c4 = (tid & 31) * 4;
    int gr = rb + rr;
    float4 v = make_float4(0.f, 0.f, 0.f, 0.f);
    if (gr < rend) v = *(const float4*)&h[(size_t)gr * 128 + c4];
    __syncthreads();
    *(float4*)&hs[rr][c4] = v;
    __syncthreads();
    #pragma unroll
    for (int r2 = 0; r2 < 8; r2++) {
      float4 a0 = *(const float4*)&hs[r2][ty * 8];
      float4 a1 = *(const float4*)&hs[r2][ty * 8 + 4];
      float4 b0 = *(const float4*)&hs[r2][tx * 8];
      float4 b1 = *(const float4*)&hs[r2][tx * 8 + 4];
      float a[8] = { a0.x,a0.y,a0.z,a0.w,a1.x,a1.y,a1.z,a1.w };
      float b[8] = { b0.x,b0.y,b0.z,b0.w,b1.x,b1.y,b1.z,b1.w };
      #pragma unroll
      for (int i = 0; i < 8; i++)
        #pragma unroll
        for (int j = 0; j < 8; j++) acc[i][j] += a[i] * b[j];
    }
  }
  #pragma unroll
  for (int i = 0; i < 8; i++)
    #pragma unroll
    for (int j = 0; j < 8; j++)
      atomicAdd(&G[(size_t)(ty * 8 + i) * 128 + tx * 8 + j], acc[i][j]);
}

// ------------------------------- megastats ---------------------------------
// One block per stat: 2x (tridiag + bisection) trace-sqrt on 128x128 Gram.
// A distributed in registers: thread (q=tid>>7, r=tid&127) owns A[r][32q..32q+31].

__global__ __launch_bounds__(512) void k_megastats(const float* __restrict__ Gall,
                                                   const float* __restrict__ colall,
                                                   const float* __restrict__ hrowall,
                                                   float* __restrict__ outstats) {
  const int blk = blockIdx.x;
  const float* G = Gall + (size_t)blk * 16384;
  const float* colsum = colall + blk * 128;
  const float* hrowg = hrowall + blk * 128;

  __shared__ float colk[128], vv[128], ww[128], qq[128];
  __shared__ float diag[128], offd[128];
  __shared__ float asS[128], b2S[128];
  __shared__ float loS[128], hiS2[128];
  __shared__ float hiRow[128], gjS[128];
  __shared__ float red4[512];
  __shared__ int cntS[512];
  __shared__ float redw[8];
  __shared__ float scal[16];
  __shared__ int ishared[4];

  const int tid = threadIdx.x;
  const int lane = tid & 63;
  const int wid = tid >> 6;
  const int q = tid >> 7;
  const int r = tid & 127;
  float Areg[32];

  // load A = sym(G)
  #pragma unroll
  for (int cc = 0; cc < 32; cc++) {
    int c = 32 * q + cc;
    Areg[cc] = 0.5f * (G[(size_t)r * 128 + c] + G[(size_t)c * 128 + r]);
  }

  for (int solve = 0; solve < 2; solve++) {
    if (q == 0) colk[r] = Areg[0];
    __syncthreads();

    // ---- Householder tridiagonalization ----
    for (int k = 0; k <= 125; k++) {
      float x = (tid < 128) ? colk[tid] : 0.f;
      float c2 = (tid < 128 && tid > k) ? x * x : 0.f;
      #pragma unroll
      for (int m = 32; m >= 1; m >>= 1) c2 += __shfl_xor(c2, m);
      if (lane == 0 && wid < 2) redw[wid] = c2;
      __syncthreads();
      if (tid == 0) {
        float sig = redw[0] + redw[1];
        float xk1 = colk[k + 1];
        float nx = sqrtf(sig);
        float alpha = (xk1 >= 0.f) ? -nx : nx;
        float vns = 2.0f * (sig - alpha * xk1);
        float rvn = (vns > 0.f) ? rsqrtf(vns) : 0.f;
        scal[0] = alpha; scal[1] = rvn;
        diag[k] = colk[k];
        offd[k] = alpha;
      }
      __syncthreads();
      if (tid < 128) {
        float alpha = scal[0], rvn = scal[1];
        float xv = colk[tid];
        vv[tid] = (tid <= k) ? 0.f : ((tid == k + 1) ? (xv - alpha) : xv) * rvn;
      }
      __syncthreads();
      // p = A v (partial per q-slice)
      {
        const float4* v4 = (const float4*)&vv[32 * q];
        float p = 0.f;
        #pragma unroll
        for (int i4 = 0; i4 < 8; i4++) {
          float4 vc = v4[i4];
          p += Areg[4*i4+0]*vc.x + Areg[4*i4+1]*vc.y + Areg[4*i4+2]*vc.z + Areg[4*i4+3]*vc.w;
        }
        red4[q * 128 + r] = p;
      }
      __syncthreads();
      if (tid < 128) {
        float p = red4[tid] + red4[128 + tid] + red4[256 + tid] + red4[384 + tid];
        ww[tid] = p;
        float vp = vv[tid] * p;
        #pragma unroll
        for (int m = 32; m >= 1; m >>= 1) vp += __shfl_xor(vp, m);
        if (lane == 0) redw[4 + wid] = vp;
      }
      __syncthreads();
      if (tid == 0) scal[2] = redw[4] + redw[5];
      __syncthreads();
      if (tid < 128) qq[tid] = 2.0f * (ww[tid] - scal[2] * vv[tid]);
      __syncthreads();
      // A -= v q^T + q v^T  ; extract next column k+1
      {
        float vr = vv[r], qr = qq[r];
        const float4* v4 = (const float4*)&vv[32 * q];
        const float4* q4 = (const float4*)&qq[32 * q];
        float nextc = 0.f;
        int kp1 = k + 1;
        #pragma unroll
        for (int i4 = 0; i4 < 8; i4++) {
          float4 vc = v4[i4], qc = q4[i4];
          int cb = 32 * q + 4 * i4;
          Areg[4*i4+0] -= vr * qc.x + qr * vc.x; if (cb + 0 == kp1) nextc = Areg[4*i4+0];
          Areg[4*i4+1] -= vr * qc.y + qr * vc.y; if (cb + 1 == kp1) nextc = Areg[4*i4+1];
          Areg[4*i4+2] -= vr * qc.z + qr * vc.z; if (cb + 2 == kp1) nextc = Areg[4*i4+2];
          Areg[4*i4+3] -= vr * qc.w + qr * vc.w; if (cb + 3 == kp1) nextc = Areg[4*i4+3];
        }
        if ((kp1 >> 5) == q) colk[r] = nextc;
      }
      __syncthreads();
    }
    if (tid == 0) { diag[126] = colk[126]; offd[126] = colk[127]; }
    if (r == 127 && q == 3) diag[127] = Areg[31];
    __syncthreads();

    // ---- Gershgorin bound ----
    if (tid < 128) {
      float t = fabsf(diag[tid]);
      if (tid > 0) t += fabsf(offd[tid - 1]);
      if (tid < 127) t += fabsf(offd[tid]);
      #pragma unroll
      for (int m = 32; m >= 1; m >>= 1) t = fmaxf(t, __shfl_xor(t, m));
      if (lane == 0) redw[wid] = t;
    }
    __syncthreads();
    if (tid == 0) {
      float g = fmaxf(redw[0], redw[1]);
      if (!(g > 1e-30f)) g = 1.f;
      scal[3] = g; scal[5] = 1.0f / g;
    }
    __syncthreads();
    if (tid < 128) {
      float ginv = scal[5];
      asS[tid] = diag[tid] * ginv;
      float ob = (tid < 127) ? offd[tid] * ginv : 0.f;
      b2S[tid] = ob * ob;
      loS[tid] = -0.0625f;
      hiS2[tid] = 1.03125f;
    }
    __syncthreads();

    // ---- multisection bisection (4 probes per eigenvalue per round) ----
    for (int round = 0; round < 12; round++) {
      int kk = tid & 127;
      int t = tid >> 7;
      float l = loS[kk], h = hiS2[kk];
      float sigma = l + (h - l) * 0.2f * (float)(t + 1);
      const float PIV = 1e-20f;
      float d = asS[0] - sigma;
      if (fabsf(d) < PIV) d = -PIV;
      int cnt = (d < 0.f) ? 1 : 0;
      for (int i = 1; i < 128; i++) {
        d = (asS[i] - sigma) - b2S[i - 1] / d;
        if (fabsf(d) < PIV) d = -PIV;
        cnt += (d < 0.f) ? 1 : 0;
      }
      cntS[tid] = cnt;
      __syncthreads();
      if (tid < 128) {
        int c0 = cntS[tid], c1 = cntS[tid + 128], c2 = cntS[tid + 256], c3 = cntS[tid + 384];
        float l2 = loS[tid], h2 = hiS2[tid];
        float w = (h2 - l2) * 0.2f;
        int cross = 4;
        if (c0 > tid) cross = 0;
        else if (c1 > tid) cross = 1;
        else if (c2 > tid) cross = 2;
        else if (c3 > tid) cross = 3;
        loS[tid] = (cross == 0) ? l2 : l2 + w * (float)cross;
        hiS2[tid] = (cross == 4) ? h2 : l2 + w * (float)(cross + 1);
      }
      __syncthreads();
    }
    // ---- sum sqrt eigenvalues ----
    if (tid < 128) {
      float lam = 0.5f * (loS[tid] + hiS2[tid]);
      lam = fmaxf(lam, 0.f) * scal[3];
      float s = sqrtf(lam);
      #pragma unroll
      for (int m = 32; m >= 1; m >>= 1) s += __shfl_xor(s, m);
      if (lane == 0) redw[wid] = s;
    }
    __syncthreads();
    if (tid == 0) scal[4] = redw[0] + redw[1];
    __syncthreads();

    if (solve == 0) {
      // prep second matrix G'
      if (tid < 128) hiRow[tid] = hrowg[tid];
      __syncthreads();
      if (tid < 128) {
        float v = colsum[tid];
        int idx = tid;
        #pragma unroll
        for (int m = 32; m >= 1; m >>= 1) {
          float v2 = __shfl_xor(v, m);
          int i2 = __shfl_xor(idx, m);
          if (v2 > v || (v2 == v && i2 < idx)) { v = v2; idx = i2; }
        }
        if (lane == 0) { redw[wid] = v; ishared[wid] = idx; }
        float hv = hiRow[tid];
        float nh = hv * hv;
        #pragma unroll
        for (int m = 32; m >= 1; m >>= 1) nh += __shfl_xor(nh, m);
        if (lane == 0) redw[4 + wid] = nh;
      }
      __syncthreads();
      if (tid == 0) {
        float v0 = redw[0], v1 = redw[1];
        int j = (v1 > v0 || (v1 == v0 && ishared[1] < ishared[0])) ? ishared[1] : ishared[0];
        float nh2 = redw[4] + redw[5];
        float nu = scal[4];
        float Gjj = G[(size_t)j * 128 + j];
        float hij = hiRow[j];
        float sflip = (hij < 0.f) ? -1.f : 1.f;
        scal[6] = 1.0f / (nu * nu);
        scal[7] = sflip / (nu * sqrtf(Gjj) * sqrtf(nh2));
        scal[8] = 1.0f / nh2;
        ishared[2] = j;
      }
      __syncthreads();
      int j = ishared[2];
      if (tid < 128) gjS[tid] = 0.5f * (G[(size_t)tid * 128 + j] + G[(size_t)j * 128 + tid]);
      __syncthreads();
      float inv2 = scal[6], c1 = scal[7], c2 = scal[8];
      float gr_ = gjS[r], hr_ = hiRow[r];
      #pragma unroll
      for (int cc = 0; cc < 32; cc++) {
        int c = 32 * q + cc;
        float gsym = 0.5f * (G[(size_t)r * 128 + c] + G[(size_t)c * 128 + r]);
        Areg[cc] = gsym * inv2 - c1 * (gr_ * hiRow[c] + hr_ * gjS[c]) + c2 * hr_ * hiRow[c];
      }
      __syncthreads();
    }
  }
  if (tid == 0) outstats[blk] = scal[4];
}

// ------------------------------- host driver -------------------------------

extern "C" void kernel_launch(void* const* d_in, const int* in_sizes, int n_in,
                              void* d_out, int out_size, void* d_ws, size_t ws_size,
                              hipStream_t stream) {
  const float* x = (const float*)d_in[0];
  const int* edge = (const int*)d_in[1];
  const float* encW = (const float*)d_in[2];
  const float* encb = (const float*)d_in[3];
  const float* W0 = (const float*)d_in[4];
  const float* b0 = (const float*)d_in[5];
  const float* W1 = (const float*)d_in[6];
  const float* b1 = (const float*)d_in[7];
  const float* W2 = (const float*)d_in[8];
  const float* b2 = (const float*)d_in[9];

  const int N = in_sizes[0] / 128;
  const int E = in_sizes[1] / 2;
  const int* esrc = edge;
  const int* edst = edge + E;

  float* out = (float*)d_out;
  float* stats_out = out + (size_t)N * 128;

  char* ws = (char*)d_ws;
  size_t offTmp = 0;
  size_t offG = offTmp + (size_t)N * 128 * 4;
  size_t offCol = offG + 4 * 16384 * 4;
  size_t offPkd = offCol + 4 * 128 * 4;
  size_t offHrow = offPkd + 4 * 8;
  size_t offDeg = offHrow + 4 * 128 * 4;
  size_t offRp = offDeg + (size_t)N * 4;
  size_t offCur = offRp + (size_t)(N + 1) * 4;
  size_t offDinv = offCur + (size_t)N * 4;
  size_t offSrc = offDinv + (size_t)N * 4;
  size_t offNrm = offSrc + (size_t)E * 4;
  size_t total = offNrm + (size_t)E * 4;
  if (ws_size < total) return;

  float* tmp = (float*)(ws + offTmp);
  float* Gall = (float*)(ws + offG);
  float* colall = (float*)(ws + offCol);
  unsigned long long* pkdall = (unsigned long long*)(ws + offPkd);
  float* hrowall = (float*)(ws + offHrow);
  unsigned* deg = (unsigned*)(ws + offDeg);
  unsigned* rowptr = (unsigned*)(ws + offRp);
  unsigned* cursor = (unsigned*)(ws + offCur);
  float* dinv = (float*)(ws + offDinv);
  int* srcs = (int*)(ws + offSrc);
  float* nrm = (float*)(ws + offNrm);

  // zero stat scratch (G, colsum, packed) and degree
  hipMemsetAsync(ws + offG, 0, 4 * 16384 * 4 + 4 * 128 * 4 + 4 * 8, stream);
  hipMemsetAsync(ws + offDeg, 0, (size_t)N * 4, stream);

  const int EB = (E + 255) / 256;
  const int NB = (N + 255) / 256;
  const int NB4 = (N + 3) / 4;
  const int GB = (N + 63) / 64;
  const int syrkRows = (N + 255) / 256;

  k_deg<<<EB, 256, 0, stream>>>(edst, deg, E);
  k_scan<<<1, 1024, 0, stream>>>(deg, rowptr, N);
  k_dinv<<<NB, 256, 0, stream>>>(deg, dinv, rowptr, cursor, N);
  k_scatter<<<EB, 256, 0, stream>>>(esrc, edst, dinv, cursor, srcs, nrm, E);

  // encoder: h0 = x @ encW.T + encb  -> d_out
  k_gemm<<<GB, 256, 0, stream>>>(x, encW, encb, out, N);
  // stat 0
  k_rowstats<<<NB4, 256, 0, stream>>>(out, colall + 0 * 128, pkdall + 0, N);
  k_syrk<<<256, 256, 0, stream>>>(out, Gall + 0 * 16384, N, syrkRows);
  k_extract<<<1, 128, 0, stream>>>(out, pkdall + 0, hrowall + 0 * 128, N);

  // layer 0
  k_gemm<<<GB, 256, 0, stream>>>(out, W0, nullptr, tmp, N);
  k_agg<true><<<NB4, 256, 0, stream>>>(tmp, rowptr, srcs, nrm, b0, out, N);
  k_rowstats<<<NB4, 256, 0, stream>>>(out, colall + 1 * 128, pkdall + 1, N);
  k_syrk<<<256, 256, 0, stream>>>(out, Gall + 1 * 16384, N, syrkRows);
  k_extract<<<1, 128, 0, stream>>>(out, pkdall + 1, hrowall + 1 * 128, N);

  // layer 1
  k_gemm<<<GB, 256, 0, stream>>>(out, W1, nullptr, tmp, N);
  k_agg<true><<<NB4, 256, 0, stream>>>(tmp, rowptr, srcs, nrm, b1, out, N);
  k_rowstats<<<NB4, 256, 0, stream>>>(out, colall + 2 * 128, pkdall + 2, N);
  k_syrk<<<256, 256, 0, stream>>>(out, Gall + 2 * 16384, N, syrkRows);
  k_extract<<<1, 128, 0, stream>>>(out, pkdall + 2, hrowall + 2 * 128, N);

  // layer 2 (no relu)
  k_gemm<<<GB, 256, 0, stream>>>(out, W2, nullptr, tmp, N);
  k_agg<false><<<NB4, 256, 0, stream>>>(tmp, rowptr, srcs, nrm, b2, out, N);
  k_rowstats<<<NB4, 256, 0, stream>>>(out, colall + 3 * 128, pkdall + 3, N);
  k_syrk<<<256, 256, 0, stream>>>(out, Gall + 3 * 16384, N, syrkRows);
  k_extract<<<1, 128, 0, stream>>>(out, pkdall + 3, hrowall + 3 * 128, N);

  // all four stats (4 blocks, each: 2x tridiag+bisection)
  k_megastats<<<4, 512, 0, stream>>>(Gall, colall, hrowall, stats_out);
}

// Round 2
// 4201.802 us; speedup vs baseline: 2.6941x; 2.6941x over previous
//
#include <hip/hip_runtime.h>
#include <hip/hip_bf16.h>

// ---------------------------------------------------------------------------
// GCN (3-layer) + encoder + rank_diff stats, all fp32.
// Round 2: register-frugal GEMM (R1 version spilled: 256 VGPR, 100x HBM traffic)
// ---------------------------------------------------------------------------

#define DIM 128

// ------------------------------- graph setup -------------------------------

__global__ void k_deg(const int* __restrict__ dst, unsigned* __restrict__ deg, int E) {
  int e = blockIdx.x * 256 + threadIdx.x;
  if (e < E) atomicAdd(&deg[dst[e]], 1u);
}

__global__ __launch_bounds__(1024) void k_scan(const unsigned* __restrict__ deg,
                                               unsigned* __restrict__ rowptr, int n) {
  __shared__ unsigned wtot[17];
  __shared__ unsigned sh_run;
  int tid = threadIdx.x;
  int lane = tid & 63, wid = tid >> 6;
  if (tid == 0) sh_run = 0;
  __syncthreads();
  for (int base = 0; base < n; base += 1024) {
    int i = base + tid;
    unsigned v = (i < n) ? deg[i] : 0u;
    unsigned s = v;
    #pragma unroll
    for (int d = 1; d < 64; d <<= 1) {
      unsigned t = __shfl_up(s, d);
      if (lane >= d) s += t;
    }
    if (lane == 63) wtot[wid] = s;
    __syncthreads();
    if (tid == 0) {
      unsigned acc = 0;
      #pragma unroll
      for (int w = 0; w < 16; w++) { unsigned t = wtot[w]; wtot[w] = acc; acc += t; }
      wtot[16] = acc;
    }
    __syncthreads();
    if (i < n) rowptr[i] = sh_run + wtot[wid] + (s - v);
    __syncthreads();
    if (tid == 0) sh_run += wtot[16];
    __syncthreads();
  }
  if (tid == 0) rowptr[n] = sh_run;
}

__global__ void k_dinv(const unsigned* __restrict__ deg, float* __restrict__ dinv,
                       const unsigned* __restrict__ rowptr, unsigned* __restrict__ cursor, int N) {
  int i = blockIdx.x * 256 + threadIdx.x;
  if (i < N) {
    unsigned d = deg[i];
    dinv[i] = d ? 1.0f / sqrtf((float)d) : 0.0f;
    cursor[i] = rowptr[i];
  }
}

__global__ void k_scatter(const int* __restrict__ src, const int* __restrict__ dst,
                          const float* __restrict__ dinv, unsigned* __restrict__ cursor,
                          int* __restrict__ srcs, float* __restrict__ nrm, int E) {
  int e = blockIdx.x * 256 + threadIdx.x;
  if (e >= E) return;
  int s = src[e], d = dst[e];
  unsigned pos = atomicAdd(&cursor[d], 1u);
  srcs[pos] = s;
  nrm[pos] = dinv[s] * dinv[d];
}

// ------------------------------- GEMM: out = A @ W.T (+bias) ----------------
// A: M x 128, W: 128 x 128 (row-major, out_dim x in_dim), out: M x 128
// 128x128 block tile, 256 threads, acc[8][8]/thread. K-tiles of 32.

__global__ __launch_bounds__(256, 2) void k_gemm(const float* __restrict__ A,
                                                 const float* __restrict__ W,
                                                 const float* __restrict__ bias,
                                                 float* __restrict__ out, int M) {
  __shared__ float Hs[32][132];   // k-major: Hs[kk][row]
  __shared__ float Ws[32][132];   // k-major: Ws[kk][col]
  const int tid = threadIdx.x;
  const int r0 = blockIdx.x * 128;
  const int tx = tid & 15, ty = tid >> 4;
  const bool full = (r0 + 128 <= M);

  float acc[8][8];
  #pragma unroll
  for (int i = 0; i < 8; i++)
    #pragma unroll
    for (int j = 0; j < 8; j++) acc[i][j] = 0.f;

  #pragma unroll 1
  for (int k0 = 0; k0 < 128; k0 += 32) {
    #pragma unroll
    for (int i = 0; i < 4; i++) {
      int f4 = i * 256 + tid;
      int row = f4 >> 3, kq = f4 & 7;
      int gr = r0 + row;
      float4 v = make_float4(0.f, 0.f, 0.f, 0.f);
      if (full || gr < M) v = *(const float4*)&A[(size_t)gr * 128 + k0 + kq * 4];
      Hs[kq * 4 + 0][row] = v.x; Hs[kq * 4 + 1][row] = v.y;
      Hs[kq * 4 + 2][row] = v.z; Hs[kq * 4 + 3][row] = v.w;
    }
    #pragma unroll
    for (int i = 0; i < 4; i++) {
      int f4 = i * 256 + tid;
      int col = f4 >> 3, kq = f4 & 7;
      float4 v = *(const float4*)&W[(size_t)col * 128 + k0 + kq * 4];
      Ws[kq * 4 + 0][col] = v.x; Ws[kq * 4 + 1][col] = v.y;
      Ws[kq * 4 + 2][col] = v.z; Ws[kq * 4 + 3][col] = v.w;
    }
    __syncthreads();
    #pragma unroll 8
    for (int kk = 0; kk < 32; kk++) {
      float4 a0 = *(const float4*)&Hs[kk][ty * 8];
      float4 a1 = *(const float4*)&Hs[kk][ty * 8 + 4];
      float4 b0 = *(const float4*)&Ws[kk][tx * 8];
      float4 b1 = *(const float4*)&Ws[kk][tx * 8 + 4];
      float a[8] = { a0.x, a0.y, a0.z, a0.w, a1.x, a1.y, a1.z, a1.w };
      float b[8] = { b0.x, b0.y, b0.z, b0.w, b1.x, b1.y, b1.z, b1.w };
      #pragma unroll
      for (int i = 0; i < 8; i++)
        #pragma unroll
        for (int j = 0; j < 8; j++) acc[i][j] += a[i] * b[j];
    }
    __syncthreads();
  }

  float bb[8] = {0.f,0.f,0.f,0.f,0.f,0.f,0.f,0.f};
  if (bias) {
    float4 v0 = *(const float4*)&bias[tx * 8];
    float4 v1 = *(const float4*)&bias[tx * 8 + 4];
    bb[0]=v0.x; bb[1]=v0.y; bb[2]=v0.z; bb[3]=v0.w;
    bb[4]=v1.x; bb[5]=v1.y; bb[6]=v1.z; bb[7]=v1.w;
  }
  #pragma unroll
  for (int i = 0; i < 8; i++) {
    int gr = r0 + ty * 8 + i;
    if (full || gr < M) {
      float4 o0 = make_float4(acc[i][0]+bb[0], acc[i][1]+bb[1], acc[i][2]+bb[2], acc[i][3]+bb[3]);
      float4 o1 = make_float4(acc[i][4]+bb[4], acc[i][5]+bb[5], acc[i][6]+bb[6], acc[i][7]+bb[7]);
      *(float4*)&out[(size_t)gr * 128 + tx * 8] = o0;
      *(float4*)&out[(size_t)gr * 128 + tx * 8 + 4] = o1;
    }
  }
}

// ------------------------------- aggregation -------------------------------

template <bool RELU>
__global__ __launch_bounds__(256) void k_agg(const float* __restrict__ tmp,
                                             const unsigned* __restrict__ rowptr,
                                             const int* __restrict__ srcs,
                                             const float* __restrict__ nrm,
                                             const float* __restrict__ bias,
                                             float* __restrict__ out, int N) {
  int wid = threadIdx.x >> 6, lane = threadIdx.x & 63;
  int n = blockIdx.x * 4 + wid;
  if (n >= N) return;
  unsigned e0 = rowptr[n], e1 = rowptr[n + 1];
  float a0 = 0.f, a1 = 0.f;
  for (unsigned e = e0; e < e1; e++) {
    int s = srcs[e];
    float w = nrm[e];
    a0 += w * tmp[(size_t)s * 128 + lane];
    a1 += w * tmp[(size_t)s * 128 + 64 + lane];
  }
  a0 += bias[lane];
  a1 += bias[64 + lane];
  if (RELU) { a0 = fmaxf(a0, 0.f); a1 = fmaxf(a1, 0.f); }
  out[(size_t)n * 128 + lane] = a0;
  out[(size_t)n * 128 + 64 + lane] = a1;
}

// ------------------------------- row/col stats -----------------------------

__global__ __launch_bounds__(256) void k_rowstats(const float* __restrict__ h,
                                                  float* __restrict__ colsum,
                                                  unsigned long long* __restrict__ packed,
                                                  int N) {
  __shared__ float cs[4][128];
  int tid = threadIdx.x, wid = tid >> 6, lane = tid & 63;
  int n = blockIdx.x * 4 + wid;
  float a0 = 0.f, a1 = 0.f;
  if (n < N) {
    a0 = fabsf(h[(size_t)n * 128 + lane]);
    a1 = fabsf(h[(size_t)n * 128 + 64 + lane]);
  }
  cs[wid][lane] = a0;
  cs[wid][64 + lane] = a1;
  float rs = a0 + a1;
  #pragma unroll
  for (int m = 32; m >= 1; m >>= 1) rs += __shfl_xor(rs, m);
  if (lane == 0 && n < N) {
    unsigned long long pk =
        ((unsigned long long)__float_as_uint(rs) << 32) |
        (unsigned long long)(0xFFFFFFFFu - (unsigned)n);
    atomicMax(packed, pk);
  }
  __syncthreads();
  if (tid < 128) {
    float s = cs[0][tid] + cs[1][tid] + cs[2][tid] + cs[3][tid];
    atomicAdd(&colsum[tid], s);
  }
}

__global__ void k_extract(const float* __restrict__ h,
                          const unsigned long long* __restrict__ packed,
                          float* __restrict__ hrow, int N) {
  unsigned long long pk = *packed;
  unsigned i = 0xFFFFFFFFu - (unsigned)(pk & 0xFFFFFFFFull);
  if (i >= (unsigned)N) i = 0;
  hrow[threadIdx.x] = h[(size_t)i * 128 + threadIdx.x];
}

// ------------------------------- SYRK: G += h^T h --------------------------

__global__ __launch_bounds__(256) void k_syrk(const float* __restrict__ h,
                                              float* __restrict__ G, int N, int rowsPer) {
  __shared__ float hs[8][132];
  int tid = threadIdx.x;
  int tx = tid & 15, ty = tid >> 4;
  float acc[8][8];
  #pragma unroll
  for (int i = 0; i < 8; i++)
    #pragma unroll
    for (int j = 0; j < 8; j++) acc[i][j] = 0.f;

  int rstart = blockIdx.x * rowsPer;
  int rend = rstart + rowsPer;
  if (rend > N) rend = N;
  for (int rb = rstart; rb < rend; rb += 8) {
    int rr = tid >> 5;
    int c4 = (tid & 31) * 4;
    int gr = rb + rr;
    float4 v = make_float4(0.f, 0.f, 0.f, 0.f);
    if (gr < rend) v = *(const float4*)&h[(size_t)gr * 128 + c4];
    __syncthreads();
    *(float4*)&hs[rr][c4] = v;
    __syncthreads();
    #pragma unroll
    for (int r2 = 0; r2 < 8; r2++) {
      float4 a0 = *(const float4*)&hs[r2][ty * 8];
      float4 a1 = *(const float4*)&hs[r2][ty * 8 + 4];
      float4 b0 = *(const float4*)&hs[r2][tx * 8];
      float4 b1 = *(const float4*)&hs[r2][tx * 8 + 4];
      float a[8] = { a0.x,a0.y,a0.z,a0.w,a1.x,a1.y,a1.z,a1.w };
      float b[8] = { b0.x,b0.y,b0.z,b0.w,b1.x,b1.y,b1.z,b1.w };
      #pragma unroll
      for (int i = 0; i < 8; i++)
        #pragma unroll
        for (int j = 0; j < 8; j++) acc[i][j] += a[i] * b[j];
    }
  }
  #pragma unroll
  for (int i = 0; i < 8; i++)
    #pragma unroll
    for (int j = 0; j < 8; j++)
      atomicAdd(&G[(size_t)(ty * 8 + i) * 128 + tx * 8 + j], acc[i][j]);
}

// ------------------------------- megastats ---------------------------------

__global__ __launch_bounds__(512) void k_megastats(const float* __restrict__ Gall,
                                                   const float* __restrict__ colall,
                                                   const float* __restrict__ hrowall,
                                                   float* __restrict__ outstats) {
  const int blk = blockIdx.x;
  const float* G = Gall + (size_t)blk * 16384;
  const float* colsum = colall + blk * 128;
  const float* hrowg = hrowall + blk * 128;

  __shared__ float colk[128], vv[128], ww[128], qq[128];
  __shared__ float diag[128], offd[128];
  __shared__ float asS[128], b2S[128];
  __shared__ float loS[128], hiS2[128];
  __shared__ float hiRow[128], gjS[128];
  __shared__ float red4[512];
  __shared__ int cntS[512];
  __shared__ float redw[8];
  __shared__ float scal[16];
  __shared__ int ishared[4];

  const int tid = threadIdx.x;
  const int lane = tid & 63;
  const int wid = tid >> 6;
  const int q = tid >> 7;
  const int r = tid & 127;
  float Areg[32];

  #pragma unroll
  for (int cc = 0; cc < 32; cc++) {
    int c = 32 * q + cc;
    Areg[cc] = 0.5f * (G[(size_t)r * 128 + c] + G[(size_t)c * 128 + r]);
  }

  for (int solve = 0; solve < 2; solve++) {
    if (q == 0) colk[r] = Areg[0];
    __syncthreads();

    for (int k = 0; k <= 125; k++) {
      float x = (tid < 128) ? colk[tid] : 0.f;
      float c2 = (tid < 128 && tid > k) ? x * x : 0.f;
      #pragma unroll
      for (int m = 32; m >= 1; m >>= 1) c2 += __shfl_xor(c2, m);
      if (lane == 0 && wid < 2) redw[wid] = c2;
      __syncthreads();
      if (tid == 0) {
        float sig = redw[0] + redw[1];
        float xk1 = colk[k + 1];
        float nx = sqrtf(sig);
        float alpha = (xk1 >= 0.f) ? -nx : nx;
        float vns = 2.0f * (sig - alpha * xk1);
        float rvn = (vns > 0.f) ? rsqrtf(vns) : 0.f;
        scal[0] = alpha; scal[1] = rvn;
        diag[k] = colk[k];
        offd[k] = alpha;
      }
      __syncthreads();
      if (tid < 128) {
        float alpha = scal[0], rvn = scal[1];
        float xv = colk[tid];
        vv[tid] = (tid <= k) ? 0.f : ((tid == k + 1) ? (xv - alpha) : xv) * rvn;
      }
      __syncthreads();
      {
        const float4* v4 = (const float4*)&vv[32 * q];
        float p = 0.f;
        #pragma unroll
        for (int i4 = 0; i4 < 8; i4++) {
          float4 vc = v4[i4];
          p += Areg[4*i4+0]*vc.x + Areg[4*i4+1]*vc.y + Areg[4*i4+2]*vc.z + Areg[4*i4+3]*vc.w;
        }
        red4[q * 128 + r] = p;
      }
      __syncthreads();
      if (tid < 128) {
        float p = red4[tid] + red4[128 + tid] + red4[256 + tid] + red4[384 + tid];
        ww[tid] = p;
        float vp = vv[tid] * p;
        #pragma unroll
        for (int m = 32; m >= 1; m >>= 1) vp += __shfl_xor(vp, m);
        if (lane == 0) redw[4 + wid] = vp;
      }
      __syncthreads();
      if (tid == 0) scal[2] = redw[4] + redw[5];
      __syncthreads();
      if (tid < 128) qq[tid] = 2.0f * (ww[tid] - scal[2] * vv[tid]);
      __syncthreads();
      {
        float vr = vv[r], qr = qq[r];
        const float4* v4 = (const float4*)&vv[32 * q];
        const float4* q4 = (const float4*)&qq[32 * q];
        float nextc = 0.f;
        int kp1 = k + 1;
        #pragma unroll
        for (int i4 = 0; i4 < 8; i4++) {
          float4 vc = v4[i4], qc = q4[i4];
          int cb = 32 * q + 4 * i4;
          Areg[4*i4+0] -= vr * qc.x + qr * vc.x; if (cb + 0 == kp1) nextc = Areg[4*i4+0];
          Areg[4*i4+1] -= vr * qc.y + qr * vc.y; if (cb + 1 == kp1) nextc = Areg[4*i4+1];
          Areg[4*i4+2] -= vr * qc.z + qr * vc.z; if (cb + 2 == kp1) nextc = Areg[4*i4+2];
          Areg[4*i4+3] -= vr * qc.w + qr * vc.w; if (cb + 3 == kp1) nextc = Areg[4*i4+3];
        }
        if ((kp1 >> 5) == q) colk[r] = nextc;
      }
      __syncthreads();
    }
    if (tid == 0) { diag[126] = colk[126]; offd[126] = colk[127]; }
    if (r == 127 && q == 3) diag[127] = Areg[31];
    __syncthreads();

    if (tid < 128) {
      float t = fabsf(diag[tid]);
      if (tid > 0) t += fabsf(offd[tid - 1]);
      if (tid < 127) t += fabsf(offd[tid]);
      #pragma unroll
      for (int m = 32; m >= 1; m >>= 1) t = fmaxf(t, __shfl_xor(t, m));
      if (lane == 0) redw[wid] = t;
    }
    __syncthreads();
    if (tid == 0) {
      float g = fmaxf(redw[0], redw[1]);
      if (!(g > 1e-30f)) g = 1.f;
      scal[3] = g; scal[5] = 1.0f / g;
    }
    __syncthreads();
    if (tid < 128) {
      float ginv = scal[5];
      asS[tid] = diag[tid] * ginv;
      float ob = (tid < 127) ? offd[tid] * ginv : 0.f;
      b2S[tid] = ob * ob;
      loS[tid] = -0.0625f;
      hiS2[tid] = 1.03125f;
    }
    __syncthreads();

    for (int round = 0; round < 12; round++) {
      int kk = tid & 127;
      int t = tid >> 7;
      float l = loS[kk], h = hiS2[kk];
      float sigma = l + (h - l) * 0.2f * (float)(t + 1);
      const float PIV = 1e-20f;
      float d = asS[0] - sigma;
      if (fabsf(d) < PIV) d = -PIV;
      int cnt = (d < 0.f) ? 1 : 0;
      for (int i = 1; i < 128; i++) {
        d = (asS[i] - sigma) - b2S[i - 1] / d;
        if (fabsf(d) < PIV) d = -PIV;
        cnt += (d < 0.f) ? 1 : 0;
      }
      cntS[tid] = cnt;
      __syncthreads();
      if (tid < 128) {
        int c0 = cntS[tid], c1 = cntS[tid + 128], c2 = cntS[tid + 256], c3 = cntS[tid + 384];
        float l2 = loS[tid], h2 = hiS2[tid];
        float w = (h2 - l2) * 0.2f;
        int cross = 4;
        if (c0 > tid) cross = 0;
        else if (c1 > tid) cross = 1;
        else if (c2 > tid) cross = 2;
        else if (c3 > tid) cross = 3;
        loS[tid] = (cross == 0) ? l2 : l2 + w * (float)cross;
        hiS2[tid] = (cross == 4) ? h2 : l2 + w * (float)(cross + 1);
      }
      __syncthreads();
    }
    if (tid < 128) {
      float lam = 0.5f * (loS[tid] + hiS2[tid]);
      lam = fmaxf(lam, 0.f) * scal[3];
      float s = sqrtf(lam);
      #pragma unroll
      for (int m = 32; m >= 1; m >>= 1) s += __shfl_xor(s, m);
      if (lane == 0) redw[wid] = s;
    }
    __syncthreads();
    if (tid == 0) scal[4] = redw[0] + redw[1];
    __syncthreads();

    if (solve == 0) {
      if (tid < 128) hiRow[tid] = hrowg[tid];
      __syncthreads();
      if (tid < 128) {
        float v = colsum[tid];
        int idx = tid;
        #pragma unroll
        for (int m = 32; m >= 1; m >>= 1) {
          float v2 = __shfl_xor(v, m);
          int i2 = __shfl_xor(idx, m);
          if (v2 > v || (v2 == v && i2 < idx)) { v = v2; idx = i2; }
        }
        if (lane == 0) { redw[wid] = v; ishared[wid] = idx; }
        float hv = hiRow[tid];
        float nh = hv * hv;
        #pragma unroll
        for (int m = 32; m >= 1; m >>= 1) nh += __shfl_xor(nh, m);
        if (lane == 0) redw[4 + wid] = nh;
      }
      __syncthreads();
      if (tid == 0) {
        float v0 = redw[0], v1 = redw[1];
        int j = (v1 > v0 || (v1 == v0 && ishared[1] < ishared[0])) ? ishared[1] : ishared[0];
        float nh2 = redw[4] + redw[5];
        float nu = scal[4];
        float Gjj = G[(size_t)j * 128 + j];
        float hij = hiRow[j];
        float sflip = (hij < 0.f) ? -1.f : 1.f;
        scal[6] = 1.0f / (nu * nu);
        scal[7] = sflip / (nu * sqrtf(Gjj) * sqrtf(nh2));
        scal[8] = 1.0f / nh2;
        ishared[2] = j;
      }
      __syncthreads();
      int j = ishared[2];
      if (tid < 128) gjS[tid] = 0.5f * (G[(size_t)tid * 128 + j] + G[(size_t)j * 128 + tid]);
      __syncthreads();
      float inv2 = scal[6], c1 = scal[7], c2 = scal[8];
      float gr_ = gjS[r], hr_ = hiRow[r];
      #pragma unroll
      for (int cc = 0; cc < 32; cc++) {
        int c = 32 * q + cc;
        float gsym = 0.5f * (G[(size_t)r * 128 + c] + G[(size_t)c * 128 + r]);
        Areg[cc] = gsym * inv2 - c1 * (gr_ * hiRow[c] + hr_ * gjS[c]) + c2 * hr_ * hiRow[c];
      }
      __syncthreads();
    }
  }
  if (tid == 0) outstats[blk] = scal[4];
}

// ------------------------------- host driver -------------------------------

extern "C" void kernel_launch(void* const* d_in, const int* in_sizes, int n_in,
                              void* d_out, int out_size, void* d_ws, size_t ws_size,
                              hipStream_t stream) {
  const float* x = (const float*)d_in[0];
  const int* edge = (const int*)d_in[1];
  const float* encW = (const float*)d_in[2];
  const float* encb = (const float*)d_in[3];
  const float* W0 = (const float*)d_in[4];
  const float* b0 = (const float*)d_in[5];
  const float* W1 = (const float*)d_in[6];
  const float* b1 = (const float*)d_in[7];
  const float* W2 = (const float*)d_in[8];
  const float* b2 = (const float*)d_in[9];

  const int N = in_sizes[0] / 128;
  const int E = in_sizes[1] / 2;
  const int* esrc = edge;
  const int* edst = edge + E;

  float* out = (float*)d_out;
  float* stats_out = out + (size_t)N * 128;

  char* ws = (char*)d_ws;
  size_t offTmp = 0;
  size_t offG = offTmp + (size_t)N * 128 * 4;
  size_t offCol = offG + 4 * 16384 * 4;
  size_t offPkd = offCol + 4 * 128 * 4;
  size_t offHrow = offPkd + 4 * 8;
  size_t offDeg = offHrow + 4 * 128 * 4;
  size_t offRp = offDeg + (size_t)N * 4;
  size_t offCur = offRp + (size_t)(N + 1) * 4;
  size_t offDinv = offCur + (size_t)N * 4;
  size_t offSrc = offDinv + (size_t)N * 4;
  size_t offNrm = offSrc + (size_t)E * 4;
  size_t total = offNrm + (size_t)E * 4;
  if (ws_size < total) return;

  float* tmp = (float*)(ws + offTmp);
  float* Gall = (float*)(ws + offG);
  float* colall = (float*)(ws + offCol);
  unsigned long long* pkdall = (unsigned long long*)(ws + offPkd);
  float* hrowall = (float*)(ws + offHrow);
  unsigned* deg = (unsigned*)(ws + offDeg);
  unsigned* rowptr = (unsigned*)(ws + offRp);
  unsigned* cursor = (unsigned*)(ws + offCur);
  float* dinv = (float*)(ws + offDinv);
  int* srcs = (int*)(ws + offSrc);
  float* nrm = (float*)(ws + offNrm);

  hipMemsetAsync(ws + offG, 0, 4 * 16384 * 4 + 4 * 128 * 4 + 4 * 8, stream);
  hipMemsetAsync(ws + offDeg, 0, (size_t)N * 4, stream);

  const int EB = (E + 255) / 256;
  const int NB = (N + 255) / 256;
  const int NB4 = (N + 3) / 4;
  const int GB = (N + 127) / 128;
  const int syrkRows = (N + 255) / 256;

  k_deg<<<EB, 256, 0, stream>>>(edst, deg, E);
  k_scan<<<1, 1024, 0, stream>>>(deg, rowptr, N);
  k_dinv<<<NB, 256, 0, stream>>>(deg, dinv, rowptr, cursor, N);
  k_scatter<<<EB, 256, 0, stream>>>(esrc, edst, dinv, cursor, srcs, nrm, E);

  // encoder: h0 = x @ encW.T + encb  -> d_out
  k_gemm<<<GB, 256, 0, stream>>>(x, encW, encb, out, N);
  k_rowstats<<<NB4, 256, 0, stream>>>(out, colall + 0 * 128, pkdall + 0, N);
  k_syrk<<<256, 256, 0, stream>>>(out, Gall + 0 * 16384, N, syrkRows);
  k_extract<<<1, 128, 0, stream>>>(out, pkdall + 0, hrowall + 0 * 128, N);

  // layer 0
  k_gemm<<<GB, 256, 0, stream>>>(out, W0, nullptr, tmp, N);
  k_agg<true><<<NB4, 256, 0, stream>>>(tmp, rowptr, srcs, nrm, b0, out, N);
  k_rowstats<<<NB4, 256, 0, stream>>>(out, colall + 1 * 128, pkdall + 1, N);
  k_syrk<<<256, 256, 0, stream>>>(out, Gall + 1 * 16384, N, syrkRows);
  k_extract<<<1, 128, 0, stream>>>(out, pkdall + 1, hrowall + 1 * 128, N);

  // layer 1
  k_gemm<<<GB, 256, 0, stream>>>(out, W1, nullptr, tmp, N);
  k_agg<true><<<NB4, 256, 0, stream>>>(tmp, rowptr, srcs, nrm, b1, out, N);
  k_rowstats<<<NB4, 256, 0, stream>>>(out, colall + 2 * 128, pkdall + 2, N);
  k_syrk<<<256, 256, 0, stream>>>(out, Gall + 2 * 16384, N, syrkRows);
  k_extract<<<1, 128, 0, stream>>>(out, pkdall + 2, hrowall + 2 * 128, N);

  // layer 2 (no relu)
  k_gemm<<<GB, 256, 0, stream>>>(out, W2, nullptr, tmp, N);
  k_agg<false><<<NB4, 256, 0, stream>>>(tmp, rowptr, srcs, nrm, b2, out, N);
  k_rowstats<<<NB4, 256, 0, stream>>>(out, colall + 3 * 128, pkdall + 3, N);
  k_syrk<<<256, 256, 0, stream>>>(out, Gall + 3 * 16384, N, syrkRows);
  k_extract<<<1, 128, 0, stream>>>(out, pkdall + 3, hrowall + 3 * 128, N);

  k_megastats<<<4, 512, 0, stream>>>(Gall, colall, hrowall, stats_out);
}

// Round 3
// 2055.444 us; speedup vs baseline: 5.5074x; 2.0442x over previous
//
#include <hip/hip_runtime.h>
#include <hip/hip_bf16.h>

// ---------------------------------------------------------------------------
// GCN (3-layer) + encoder + rank_diff stats, all fp32.
// R3: megastats 4-barrier Householder + active-slice skip + fast-rcp Sturm;
//     rowstats 16-node blocks (atomic contention fix); agg unroll-2 prefetch.
// ---------------------------------------------------------------------------

#define DIM 128

// ------------------------------- graph setup -------------------------------

__global__ void k_deg(const int* __restrict__ dst, unsigned* __restrict__ deg, int E) {
  int e = blockIdx.x * 256 + threadIdx.x;
  if (e < E) atomicAdd(&deg[dst[e]], 1u);
}

__global__ __launch_bounds__(1024) void k_scan(const unsigned* __restrict__ deg,
                                               unsigned* __restrict__ rowptr, int n) {
  __shared__ unsigned wtot[17];
  __shared__ unsigned sh_run;
  int tid = threadIdx.x;
  int lane = tid & 63, wid = tid >> 6;
  if (tid == 0) sh_run = 0;
  __syncthreads();
  for (int base = 0; base < n; base += 1024) {
    int i = base + tid;
    unsigned v = (i < n) ? deg[i] : 0u;
    unsigned s = v;
    #pragma unroll
    for (int d = 1; d < 64; d <<= 1) {
      unsigned t = __shfl_up(s, d);
      if (lane >= d) s += t;
    }
    if (lane == 63) wtot[wid] = s;
    __syncthreads();
    if (tid == 0) {
      unsigned acc = 0;
      #pragma unroll
      for (int w = 0; w < 16; w++) { unsigned t = wtot[w]; wtot[w] = acc; acc += t; }
      wtot[16] = acc;
    }
    __syncthreads();
    if (i < n) rowptr[i] = sh_run + wtot[wid] + (s - v);
    __syncthreads();
    if (tid == 0) sh_run += wtot[16];
    __syncthreads();
  }
  if (tid == 0) rowptr[n] = sh_run;
}

__global__ void k_dinv(const unsigned* __restrict__ deg, float* __restrict__ dinv,
                       const unsigned* __restrict__ rowptr, unsigned* __restrict__ cursor, int N) {
  int i = blockIdx.x * 256 + threadIdx.x;
  if (i < N) {
    unsigned d = deg[i];
    dinv[i] = d ? 1.0f / sqrtf((float)d) : 0.0f;
    cursor[i] = rowptr[i];
  }
}

__global__ void k_scatter(const int* __restrict__ src, const int* __restrict__ dst,
                          const float* __restrict__ dinv, unsigned* __restrict__ cursor,
                          int* __restrict__ srcs, float* __restrict__ nrm, int E) {
  int e = blockIdx.x * 256 + threadIdx.x;
  if (e >= E) return;
  int s = src[e], d = dst[e];
  unsigned pos = atomicAdd(&cursor[d], 1u);
  srcs[pos] = s;
  nrm[pos] = dinv[s] * dinv[d];
}

// ------------------------------- GEMM: out = A @ W.T (+bias) ----------------

__global__ __launch_bounds__(256, 2) void k_gemm(const float* __restrict__ A,
                                                 const float* __restrict__ W,
                                                 const float* __restrict__ bias,
                                                 float* __restrict__ out, int M) {
  __shared__ float Hs[32][132];   // k-major: Hs[kk][row]
  __shared__ float Ws[32][132];   // k-major: Ws[kk][col]
  const int tid = threadIdx.x;
  const int r0 = blockIdx.x * 128;
  const int tx = tid & 15, ty = tid >> 4;
  const bool full = (r0 + 128 <= M);

  float acc[8][8];
  #pragma unroll
  for (int i = 0; i < 8; i++)
    #pragma unroll
    for (int j = 0; j < 8; j++) acc[i][j] = 0.f;

  #pragma unroll 1
  for (int k0 = 0; k0 < 128; k0 += 32) {
    #pragma unroll
    for (int i = 0; i < 4; i++) {
      int f4 = i * 256 + tid;
      int row = f4 >> 3, kq = f4 & 7;
      int gr = r0 + row;
      float4 v = make_float4(0.f, 0.f, 0.f, 0.f);
      if (full || gr < M) v = *(const float4*)&A[(size_t)gr * 128 + k0 + kq * 4];
      Hs[kq * 4 + 0][row] = v.x; Hs[kq * 4 + 1][row] = v.y;
      Hs[kq * 4 + 2][row] = v.z; Hs[kq * 4 + 3][row] = v.w;
    }
    #pragma unroll
    for (int i = 0; i < 4; i++) {
      int f4 = i * 256 + tid;
      int col = f4 >> 3, kq = f4 & 7;
      float4 v = *(const float4*)&W[(size_t)col * 128 + k0 + kq * 4];
      Ws[kq * 4 + 0][col] = v.x; Ws[kq * 4 + 1][col] = v.y;
      Ws[kq * 4 + 2][col] = v.z; Ws[kq * 4 + 3][col] = v.w;
    }
    __syncthreads();
    #pragma unroll 8
    for (int kk = 0; kk < 32; kk++) {
      float4 a0 = *(const float4*)&Hs[kk][ty * 8];
      float4 a1 = *(const float4*)&Hs[kk][ty * 8 + 4];
      float4 b0 = *(const float4*)&Ws[kk][tx * 8];
      float4 b1 = *(const float4*)&Ws[kk][tx * 8 + 4];
      float a[8] = { a0.x, a0.y, a0.z, a0.w, a1.x, a1.y, a1.z, a1.w };
      float b[8] = { b0.x, b0.y, b0.z, b0.w, b1.x, b1.y, b1.z, b1.w };
      #pragma unroll
      for (int i = 0; i < 8; i++)
        #pragma unroll
        for (int j = 0; j < 8; j++) acc[i][j] += a[i] * b[j];
    }
    __syncthreads();
  }

  float bb[8] = {0.f,0.f,0.f,0.f,0.f,0.f,0.f,0.f};
  if (bias) {
    float4 v0 = *(const float4*)&bias[tx * 8];
    float4 v1 = *(const float4*)&bias[tx * 8 + 4];
    bb[0]=v0.x; bb[1]=v0.y; bb[2]=v0.z; bb[3]=v0.w;
    bb[4]=v1.x; bb[5]=v1.y; bb[6]=v1.z; bb[7]=v1.w;
  }
  #pragma unroll
  for (int i = 0; i < 8; i++) {
    int gr = r0 + ty * 8 + i;
    if (full || gr < M) {
      float4 o0 = make_float4(acc[i][0]+bb[0], acc[i][1]+bb[1], acc[i][2]+bb[2], acc[i][3]+bb[3]);
      float4 o1 = make_float4(acc[i][4]+bb[4], acc[i][5]+bb[5], acc[i][6]+bb[6], acc[i][7]+bb[7]);
      *(float4*)&out[(size_t)gr * 128 + tx * 8] = o0;
      *(float4*)&out[(size_t)gr * 128 + tx * 8 + 4] = o1;
    }
  }
}

// ------------------------------- aggregation -------------------------------

template <bool RELU>
__global__ __launch_bounds__(256) void k_agg(const float* __restrict__ tmp,
                                             const unsigned* __restrict__ rowptr,
                                             const int* __restrict__ srcs,
                                             const float* __restrict__ nrm,
                                             const float* __restrict__ bias,
                                             float* __restrict__ out, int N) {
  int wid = threadIdx.x >> 6, lane = threadIdx.x & 63;
  int n = blockIdx.x * 4 + wid;
  if (n >= N) return;
  unsigned e0 = rowptr[n], e1 = rowptr[n + 1];
  float a0 = 0.f, a1 = 0.f;
  unsigned e = e0;
  for (; e + 2 <= e1; e += 2) {
    int s0 = srcs[e], s1 = srcs[e + 1];
    float w0 = nrm[e], w1 = nrm[e + 1];
    const float* p0 = tmp + (size_t)s0 * 128;
    const float* p1 = tmp + (size_t)s1 * 128;
    float x00 = p0[lane], x01 = p0[64 + lane];
    float x10 = p1[lane], x11 = p1[64 + lane];
    a0 += w0 * x00 + w1 * x10;
    a1 += w0 * x01 + w1 * x11;
  }
  if (e < e1) {
    int s = srcs[e];
    float w = nrm[e];
    a0 += w * tmp[(size_t)s * 128 + lane];
    a1 += w * tmp[(size_t)s * 128 + 64 + lane];
  }
  a0 += bias[lane];
  a1 += bias[64 + lane];
  if (RELU) { a0 = fmaxf(a0, 0.f); a1 = fmaxf(a1, 0.f); }
  out[(size_t)n * 128 + lane] = a0;
  out[(size_t)n * 128 + 64 + lane] = a1;
}

// ------------------------------- row/col stats -----------------------------
// 16 nodes per block; LDS-combined colsum + single packed atomicMax per block.

__global__ __launch_bounds__(256) void k_rowstats(const float* __restrict__ h,
                                                  float* __restrict__ colsum,
                                                  unsigned long long* __restrict__ packed,
                                                  int N) {
  __shared__ float cs[128];
  __shared__ unsigned long long wmaxS[4];
  int tid = threadIdx.x, wid = tid >> 6, lane = tid & 63;
  if (tid < 128) cs[tid] = 0.f;
  __syncthreads();
  int base = blockIdx.x * 16;
  float c0 = 0.f, c1 = 0.f;
  unsigned long long wmax = 0;
  #pragma unroll
  for (int g = 0; g < 4; g++) {
    int n = base + g * 4 + wid;
    float a0 = 0.f, a1 = 0.f;
    if (n < N) {
      a0 = fabsf(h[(size_t)n * 128 + lane]);
      a1 = fabsf(h[(size_t)n * 128 + 64 + lane]);
    }
    c0 += a0; c1 += a1;
    float rs = a0 + a1;
    #pragma unroll
    for (int m = 32; m >= 1; m >>= 1) rs += __shfl_xor(rs, m);
    if (lane == 0 && n < N) {
      unsigned long long pk =
          ((unsigned long long)__float_as_uint(rs) << 32) |
          (unsigned long long)(0xFFFFFFFFu - (unsigned)n);
      if (pk > wmax) wmax = pk;
    }
  }
  atomicAdd(&cs[lane], c0);
  atomicAdd(&cs[64 + lane], c1);
  if (lane == 0) wmaxS[wid] = wmax;
  __syncthreads();
  if (tid == 0) {
    unsigned long long m = wmaxS[0];
    if (wmaxS[1] > m) m = wmaxS[1];
    if (wmaxS[2] > m) m = wmaxS[2];
    if (wmaxS[3] > m) m = wmaxS[3];
    atomicMax(packed, m);
  }
  if (tid < 128) atomicAdd(&colsum[tid], cs[tid]);
}

__global__ void k_extract(const float* __restrict__ h,
                          const unsigned long long* __restrict__ packed,
                          float* __restrict__ hrow, int N) {
  unsigned long long pk = *packed;
  unsigned i = 0xFFFFFFFFu - (unsigned)(pk & 0xFFFFFFFFull);
  if (i >= (unsigned)N) i = 0;
  hrow[threadIdx.x] = h[(size_t)i * 128 + threadIdx.x];
}

// ------------------------------- SYRK: G += h^T h --------------------------

__global__ __launch_bounds__(256) void k_syrk(const float* __restrict__ h,
                                              float* __restrict__ G, int N, int rowsPer) {
  __shared__ float hs[8][132];
  int tid = threadIdx.x;
  int tx = tid & 15, ty = tid >> 4;
  float acc[8][8];
  #pragma unroll
  for (int i = 0; i < 8; i++)
    #pragma unroll
    for (int j = 0; j < 8; j++) acc[i][j] = 0.f;

  int rstart = blockIdx.x * rowsPer;
  int rend = rstart + rowsPer;
  if (rend > N) rend = N;
  for (int rb = rstart; rb < rend; rb += 8) {
    int rr = tid >> 5;
    int c4 = (tid & 31) * 4;
    int gr = rb + rr;
    float4 v = make_float4(0.f, 0.f, 0.f, 0.f);
    if (gr < rend) v = *(const float4*)&h[(size_t)gr * 128 + c4];
    __syncthreads();
    *(float4*)&hs[rr][c4] = v;
    __syncthreads();
    #pragma unroll
    for (int r2 = 0; r2 < 8; r2++) {
      float4 a0 = *(const float4*)&hs[r2][ty * 8];
      float4 a1 = *(const float4*)&hs[r2][ty * 8 + 4];
      float4 b0 = *(const float4*)&hs[r2][tx * 8];
      float4 b1 = *(const float4*)&hs[r2][tx * 8 + 4];
      float a[8] = { a0.x,a0.y,a0.z,a0.w,a1.x,a1.y,a1.z,a1.w };
      float b[8] = { b0.x,b0.y,b0.z,b0.w,b1.x,b1.y,b1.z,b1.w };
      #pragma unroll
      for (int i = 0; i < 8; i++)
        #pragma unroll
        for (int j = 0; j < 8; j++) acc[i][j] += a[i] * b[j];
    }
  }
  #pragma unroll
  for (int i = 0; i < 8; i++)
    #pragma unroll
    for (int j = 0; j < 8; j++)
      atomicAdd(&G[(size_t)(ty * 8 + i) * 128 + tx * 8 + j], acc[i][j]);
}

// ------------------------------- megastats ---------------------------------
// One block per stat: 2x (tridiag + bisection) trace-sqrt on 128x128 Gram.
// 4 barriers per Householder step; scalars recomputed redundantly by all
// threads from LDS partials; q formed on the fly from ww/vv; next-column
// sigma reduction fused into the rank-2 update.

__global__ __launch_bounds__(512) void k_megastats(const float* __restrict__ Gall,
                                                   const float* __restrict__ colall,
                                                   const float* __restrict__ hrowall,
                                                   float* __restrict__ outstats) {
  const int blk = blockIdx.x;
  const float* G = Gall + (size_t)blk * 16384;
  const float* colsum = colall + blk * 128;
  const float* hrowg = hrowall + blk * 128;

  __shared__ float colk[128], vv[128], ww[128];
  __shared__ float diag[128], offd[128];
  __shared__ float asS[128], b2S[128];
  __shared__ float loS[128], hiS[128];
  __shared__ float hiRow[128], gjS[128];
  __shared__ float red4[512];
  __shared__ int cntS[512];
  __shared__ float redw[8];
  __shared__ float scal[16];
  __shared__ int ishared[4];

  const int tid = threadIdx.x;
  const int lane = tid & 63;
  const int wid = tid >> 6;
  const int q = tid >> 7;
  const int r = tid & 127;
  const int cbase = 32 * q;
  float Areg[32];

  #pragma unroll
  for (int cc = 0; cc < 32; cc++) {
    int c = cbase + cc;
    Areg[cc] = 0.5f * (G[(size_t)r * 128 + c] + G[(size_t)c * 128 + r]);
  }

  for (int solve = 0; solve < 2; solve++) {
    // init: column 0 + its sigma partials
    if (q == 0) colk[r] = Areg[0];
    __syncthreads();
    if (q == 0) {
      float x = colk[r];
      float c2 = (r > 0) ? x * x : 0.f;
      #pragma unroll
      for (int m = 32; m >= 1; m >>= 1) c2 += __shfl_xor(c2, m);
      if (lane == 0) redw[wid] = c2;
    }
    __syncthreads();

    for (int k = 0; k <= 125; k++) {
      // S1: scalars (redundant on all threads) + v
      float sig = redw[0] + redw[1];
      float xk1 = colk[k + 1];
      float nx = sqrtf(sig);
      float alpha = (xk1 >= 0.f) ? -nx : nx;
      float vns = 2.0f * (sig - alpha * xk1);
      float rvn = (vns > 1e-35f) ? rsqrtf(vns) : 0.f;
      if (tid == 0) { diag[k] = colk[k]; offd[k] = alpha; }
      if (q == 0) {
        float xv = colk[r];
        vv[r] = (r <= k) ? 0.f : ((r == k + 1) ? (xv - alpha) : xv) * rvn;
      }
      __syncthreads();

      // S2: partial p = A v over this thread's column slice
      const bool active = (cbase + 31 >= k);
      float p = 0.f;
      if (active) {
        const float4* v4 = (const float4*)&vv[cbase];
        #pragma unroll
        for (int i4 = 0; i4 < 8; i4++) {
          float4 vc = v4[i4];
          p += Areg[4*i4+0]*vc.x + Areg[4*i4+1]*vc.y + Areg[4*i4+2]*vc.z + Areg[4*i4+3]*vc.w;
        }
      }
      red4[q * 128 + r] = p;
      __syncthreads();

      // S3: full p, ww, and v^T p partials
      if (q == 0) {
        float pp = red4[r] + red4[128 + r] + red4[256 + r] + red4[384 + r];
        ww[r] = pp;
        float vp = vv[r] * pp;
        #pragma unroll
        for (int m = 32; m >= 1; m >>= 1) vp += __shfl_xor(vp, m);
        if (lane == 0) redw[4 + wid] = vp;
      }
      __syncthreads();

      // S4: rank-2 update + extract col k+1 + its sigma partials
      float lam = redw[4] + redw[5];
      int kp1 = k + 1, qo = kp1 >> 5;
      if (active) {
        float vr = vv[r], wr = ww[r];
        float qr = 2.0f * (wr - lam * vr);
        const float4* v4 = (const float4*)&vv[cbase];
        const float4* w4 = (const float4*)&ww[cbase];
        float nextc = 0.f;
        #pragma unroll
        for (int i4 = 0; i4 < 8; i4++) {
          float4 vc = v4[i4], wc = w4[i4];
          int cb = cbase + 4 * i4;
          float q0_ = 2.f*(wc.x - lam*vc.x); Areg[4*i4+0] -= vr*q0_ + qr*vc.x; if (cb+0 == kp1) nextc = Areg[4*i4+0];
          float q1_ = 2.f*(wc.y - lam*vc.y); Areg[4*i4+1] -= vr*q1_ + qr*vc.y; if (cb+1 == kp1) nextc = Areg[4*i4+1];
          float q2_ = 2.f*(wc.z - lam*vc.z); Areg[4*i4+2] -= vr*q2_ + qr*vc.z; if (cb+2 == kp1) nextc = Areg[4*i4+2];
          float q3_ = 2.f*(wc.w - lam*vc.w); Areg[4*i4+3] -= vr*q3_ + qr*vc.w; if (cb+3 == kp1) nextc = Areg[4*i4+3];
        }
        if (q == qo) {
          colk[r] = nextc;
          float m2 = (r > kp1) ? nextc * nextc : 0.f;
          #pragma unroll
          for (int m = 32; m >= 1; m >>= 1) m2 += __shfl_xor(m2, m);
          if (lane == 0) redw[r >> 6] = m2;
        }
      }
      __syncthreads();
    }
    if (tid == 0) { diag[126] = colk[126]; offd[126] = colk[127]; }
    if (q == 3 && r == 127) diag[127] = Areg[31];
    __syncthreads();

    // ---- Gershgorin bound ----
    if (tid < 128) {
      float t = fabsf(diag[tid]);
      if (tid > 0) t += fabsf(offd[tid - 1]);
      if (tid < 127) t += fabsf(offd[tid]);
      #pragma unroll
      for (int m = 32; m >= 1; m >>= 1) t = fmaxf(t, __shfl_xor(t, m));
      if (lane == 0) redw[wid] = t;
    }
    __syncthreads();
    if (tid == 0) {
      float g = fmaxf(redw[0], redw[1]);
      if (!(g > 1e-30f)) g = 1.f;
      scal[3] = g; scal[5] = 1.0f / g;
    }
    __syncthreads();
    if (tid < 128) {
      float ginv = scal[5];
      asS[tid] = diag[tid] * ginv;
      float ob = (tid < 127) ? offd[tid] * ginv : 0.f;
      b2S[tid] = ob * ob;
      loS[tid] = -0.0625f;
      hiS[tid] = 1.03125f;
    }
    __syncthreads();

    // ---- multisection bisection (4 probes per eigenvalue per round) ----
    for (int round = 0; round < 12; round++) {
      int kk = tid & 127;
      int t = tid >> 7;
      float l = loS[kk], h = hiS[kk];
      float sigma = l + (h - l) * 0.2f * (float)(t + 1);
      const float PIV = 1e-20f;
      float d = asS[0] - sigma;
      if (fabsf(d) < PIV) d = -PIV;
      int cnt = (d < 0.f) ? 1 : 0;
      for (int i = 1; i < 128; i++) {
        d = (asS[i] - sigma) - b2S[i - 1] * __builtin_amdgcn_rcpf(d);
        if (fabsf(d) < PIV) d = -PIV;
        cnt += (d < 0.f) ? 1 : 0;
      }
      cntS[tid] = cnt;
      __syncthreads();
      if (tid < 128) {
        int c0 = cntS[tid], c1 = cntS[tid + 128], c2 = cntS[tid + 256], c3 = cntS[tid + 384];
        float l2 = loS[tid], h2 = hiS[tid];
        float w = (h2 - l2) * 0.2f;
        int cross = 4;
        if (c0 > tid) cross = 0;
        else if (c1 > tid) cross = 1;
        else if (c2 > tid) cross = 2;
        else if (c3 > tid) cross = 3;
        loS[tid] = (cross == 0) ? l2 : l2 + w * (float)cross;
        hiS[tid] = (cross == 4) ? h2 : l2 + w * (float)(cross + 1);
      }
      __syncthreads();
    }
    // ---- sum sqrt eigenvalues ----
    if (tid < 128) {
      float lam = 0.5f * (loS[tid] + hiS[tid]);
      lam = fmaxf(lam, 0.f) * scal[3];
      float s = sqrtf(lam);
      #pragma unroll
      for (int m = 32; m >= 1; m >>= 1) s += __shfl_xor(s, m);
      if (lane == 0) redw[wid] = s;
    }
    __syncthreads();
    if (tid == 0) scal[4] = redw[0] + redw[1];
    __syncthreads();

    if (solve == 0) {
      // build second matrix G'
      if (tid < 128) hiRow[tid] = hrowg[tid];
      __syncthreads();
      if (tid < 128) {
        float v = colsum[tid];
        int idx = tid;
        #pragma unroll
        for (int m = 32; m >= 1; m >>= 1) {
          float v2 = __shfl_xor(v, m);
          int i2 = __shfl_xor(idx, m);
          if (v2 > v || (v2 == v && i2 < idx)) { v = v2; idx = i2; }
        }
        if (lane == 0) { redw[wid] = v; ishared[wid] = idx; }
        float hv = hiRow[tid];
        float nh = hv * hv;
        #pragma unroll
        for (int m = 32; m >= 1; m >>= 1) nh += __shfl_xor(nh, m);
        if (lane == 0) redw[4 + wid] = nh;
      }
      __syncthreads();
      if (tid == 0) {
        float v0 = redw[0], v1 = redw[1];
        int j = (v1 > v0 || (v1 == v0 && ishared[1] < ishared[0])) ? ishared[1] : ishared[0];
        float nh2 = redw[4] + redw[5];
        float nu = scal[4];
        float Gjj = G[(size_t)j * 128 + j];
        float hij = hiRow[j];
        float sflip = (hij < 0.f) ? -1.f : 1.f;
        scal[6] = 1.0f / (nu * nu);
        scal[7] = sflip / (nu * sqrtf(Gjj) * sqrtf(nh2));
        scal[8] = 1.0f / nh2;
        ishared[2] = j;
      }
      __syncthreads();
      int j = ishared[2];
      if (tid < 128) gjS[tid] = 0.5f * (G[(size_t)tid * 128 + j] + G[(size_t)j * 128 + tid]);
      __syncthreads();
      float inv2 = scal[6], c1 = scal[7], c2 = scal[8];
      float gr_ = gjS[r], hr_ = hiRow[r];
      #pragma unroll
      for (int cc = 0; cc < 32; cc++) {
        int c = cbase + cc;
        float gsym = 0.5f * (G[(size_t)r * 128 + c] + G[(size_t)c * 128 + r]);
        Areg[cc] = gsym * inv2 - c1 * (gr_ * hiRow[c] + hr_ * gjS[c]) + c2 * hr_ * hiRow[c];
      }
      __syncthreads();
    }
  }
  if (tid == 0) outstats[blk] = scal[4];
}

// ------------------------------- host driver -------------------------------

extern "C" void kernel_launch(void* const* d_in, const int* in_sizes, int n_in,
                              void* d_out, int out_size, void* d_ws, size_t ws_size,
                              hipStream_t stream) {
  const float* x = (const float*)d_in[0];
  const int* edge = (const int*)d_in[1];
  const float* encW = (const float*)d_in[2];
  const float* encb = (const float*)d_in[3];
  const float* W0 = (const float*)d_in[4];
  const float* b0 = (const float*)d_in[5];
  const float* W1 = (const float*)d_in[6];
  const float* b1 = (const float*)d_in[7];
  const float* W2 = (const float*)d_in[8];
  const float* b2 = (const float*)d_in[9];

  const int N = in_sizes[0] / 128;
  const int E = in_sizes[1] / 2;
  const int* esrc = edge;
  const int* edst = edge + E;

  float* out = (float*)d_out;
  float* stats_out = out + (size_t)N * 128;

  char* ws = (char*)d_ws;
  size_t offTmp = 0;
  size_t offG = offTmp + (size_t)N * 128 * 4;
  size_t offCol = offG + 4 * 16384 * 4;
  size_t offPkd = offCol + 4 * 128 * 4;
  size_t offHrow = offPkd + 4 * 8;
  size_t offDeg = offHrow + 4 * 128 * 4;
  size_t offRp = offDeg + (size_t)N * 4;
  size_t offCur = offRp + (size_t)(N + 1) * 4;
  size_t offDinv = offCur + (size_t)N * 4;
  size_t offSrc = offDinv + (size_t)N * 4;
  size_t offNrm = offSrc + (size_t)E * 4;
  size_t total = offNrm + (size_t)E * 4;
  if (ws_size < total) return;

  float* tmp = (float*)(ws + offTmp);
  float* Gall = (float*)(ws + offG);
  float* colall = (float*)(ws + offCol);
  unsigned long long* pkdall = (unsigned long long*)(ws + offPkd);
  float* hrowall = (float*)(ws + offHrow);
  unsigned* deg = (unsigned*)(ws + offDeg);
  unsigned* rowptr = (unsigned*)(ws + offRp);
  unsigned* cursor = (unsigned*)(ws + offCur);
  float* dinv = (float*)(ws + offDinv);
  int* srcs = (int*)(ws + offSrc);
  float* nrm = (float*)(ws + offNrm);

  hipMemsetAsync(ws + offG, 0, 4 * 16384 * 4 + 4 * 128 * 4 + 4 * 8, stream);
  hipMemsetAsync(ws + offDeg, 0, (size_t)N * 4, stream);

  const int EB = (E + 255) / 256;
  const int NB = (N + 255) / 256;
  const int NB4 = (N + 3) / 4;
  const int NB16 = (N + 15) / 16;
  const int GB = (N + 127) / 128;
  const int syrkRows = (N + 255) / 256;

  k_deg<<<EB, 256, 0, stream>>>(edst, deg, E);
  k_scan<<<1, 1024, 0, stream>>>(deg, rowptr, N);
  k_dinv<<<NB, 256, 0, stream>>>(deg, dinv, rowptr, cursor, N);
  k_scatter<<<EB, 256, 0, stream>>>(esrc, edst, dinv, cursor, srcs, nrm, E);

  // encoder: h0 = x @ encW.T + encb  -> d_out
  k_gemm<<<GB, 256, 0, stream>>>(x, encW, encb, out, N);
  k_rowstats<<<NB16, 256, 0, stream>>>(out, colall + 0 * 128, pkdall + 0, N);
  k_syrk<<<256, 256, 0, stream>>>(out, Gall + 0 * 16384, N, syrkRows);
  k_extract<<<1, 128, 0, stream>>>(out, pkdall + 0, hrowall + 0 * 128, N);

  // layer 0
  k_gemm<<<GB, 256, 0, stream>>>(out, W0, nullptr, tmp, N);
  k_agg<true><<<NB4, 256, 0, stream>>>(tmp, rowptr, srcs, nrm, b0, out, N);
  k_rowstats<<<NB16, 256, 0, stream>>>(out, colall + 1 * 128, pkdall + 1, N);
  k_syrk<<<256, 256, 0, stream>>>(out, Gall + 1 * 16384, N, syrkRows);
  k_extract<<<1, 128, 0, stream>>>(out, pkdall + 1, hrowall + 1 * 128, N);

  // layer 1
  k_gemm<<<GB, 256, 0, stream>>>(out, W1, nullptr, tmp, N);
  k_agg<true><<<NB4, 256, 0, stream>>>(tmp, rowptr, srcs, nrm, b1, out, N);
  k_rowstats<<<NB16, 256, 0, stream>>>(out, colall + 2 * 128, pkdall + 2, N);
  k_syrk<<<256, 256, 0, stream>>>(out, Gall + 2 * 16384, N, syrkRows);
  k_extract<<<1, 128, 0, stream>>>(out, pkdall + 2, hrowall + 2 * 128, N);

  // layer 2 (no relu)
  k_gemm<<<GB, 256, 0, stream>>>(out, W2, nullptr, tmp, N);
  k_agg<false><<<NB4, 256, 0, stream>>>(tmp, rowptr, srcs, nrm, b2, out, N);
  k_rowstats<<<NB16, 256, 0, stream>>>(out, colall + 3 * 128, pkdall + 3, N);
  k_syrk<<<256, 256, 0, stream>>>(out, Gall + 3 * 16384, N, syrkRows);
  k_extract<<<1, 128, 0, stream>>>(out, pkdall + 3, hrowall + 3 * 128, N);

  k_megastats<<<4, 512, 0, stream>>>(Gall, colall, hrowall, stats_out);
}

// Round 4
// 1919.467 us; speedup vs baseline: 5.8975x; 1.0708x over previous
//
#include <hip/hip_runtime.h>
#include <hip/hip_bf16.h>

// ---------------------------------------------------------------------------
// GCN (3-layer) + encoder + rank_diff stats, all fp32.
// R4: megastats 2-barrier Householder with DPP reductions + colk zero-invariant;
//     rowstats fused into syrk; multi-block scan; agg float2.
// ---------------------------------------------------------------------------

#define DIM 128

// DPP helpers: CTRL 0xB1=quad_perm[1,0,3,2] (xor1), 0x4E=quad_perm[2,3,0,1] (xor2),
// 0x124=row_ror:4, 0x128=row_ror:8, 0x142=row_bcast15.
template <int CTRL>
__device__ __forceinline__ float dpp_add(float v) {
  int x = __builtin_amdgcn_update_dpp(0, __float_as_int(v), CTRL, 0xF, 0xF, true);
  return v + __int_as_float(x);
}

__device__ __forceinline__ float sum32u(const float* s) {
  const float4* s4 = (const float4*)s;
  float4 a = s4[0], b = s4[1], c = s4[2], d = s4[3];
  float4 e = s4[4], f = s4[5], g = s4[6], h = s4[7];
  float t0 = (a.x + a.y) + (a.z + a.w);
  float t1 = (b.x + b.y) + (b.z + b.w);
  float t2 = (c.x + c.y) + (c.z + c.w);
  float t3 = (d.x + d.y) + (d.z + d.w);
  float t4 = (e.x + e.y) + (e.z + e.w);
  float t5 = (f.x + f.y) + (f.z + f.w);
  float t6 = (g.x + g.y) + (g.z + g.w);
  float t7 = (h.x + h.y) + (h.z + h.w);
  return ((t0 + t1) + (t2 + t3)) + ((t4 + t5) + (t6 + t7));
}

// ------------------------------- graph setup -------------------------------

__global__ void k_deg(const int* __restrict__ dst, unsigned* __restrict__ deg, int E) {
  int e = blockIdx.x * 256 + threadIdx.x;
  if (e < E) atomicAdd(&deg[dst[e]], 1u);
}

__global__ __launch_bounds__(1024) void k_scan1(const unsigned* __restrict__ deg,
                                                unsigned* __restrict__ loc,
                                                unsigned* __restrict__ part, int n) {
  __shared__ unsigned wtot[16];
  int tid = threadIdx.x, lane = tid & 63, wid = tid >> 6;
  int i = blockIdx.x * 1024 + tid;
  unsigned v = (i < n) ? deg[i] : 0u;
  unsigned s = v;
  #pragma unroll
  for (int d = 1; d < 64; d <<= 1) {
    unsigned t = __shfl_up(s, d);
    if (lane >= d) s += t;
  }
  if (lane == 63) wtot[wid] = s;
  __syncthreads();
  if (tid == 0) {
    unsigned acc = 0;
    #pragma unroll
    for (int w = 0; w < 16; w++) { unsigned t = wtot[w]; wtot[w] = acc; acc += t; }
    part[blockIdx.x] = acc;
  }
  __syncthreads();
  if (i < n) loc[i] = wtot[wid] + (s - v);
}

__global__ void k_scan2(unsigned* part, int nb) {
  int tid = threadIdx.x;  // 64 threads, nb <= 64
  unsigned v = (tid < nb) ? part[tid] : 0u;
  unsigned s = v;
  #pragma unroll
  for (int d = 1; d < 64; d <<= 1) {
    unsigned t = __shfl_up(s, d);
    if (tid >= d) s += t;
  }
  if (tid < nb) part[tid] = s - v;
  if (tid == 63) part[nb] = s;
}

__global__ __launch_bounds__(1024) void k_scan3(const unsigned* __restrict__ deg,
                                                const unsigned* __restrict__ part,
                                                unsigned* __restrict__ rowptr,
                                                unsigned* __restrict__ loc_cursor,
                                                float* __restrict__ dinv, int n, int nb) {
  int i = blockIdx.x * 1024 + threadIdx.x;
  if (i < n) {
    unsigned v = loc_cursor[i] + part[blockIdx.x];
    rowptr[i] = v;
    loc_cursor[i] = v;
    unsigned d = deg[i];
    dinv[i] = d ? 1.0f / sqrtf((float)d) : 0.0f;
  }
  if (i == 0) rowptr[n] = part[nb];
}

__global__ void k_scatter(const int* __restrict__ src, const int* __restrict__ dst,
                          const float* __restrict__ dinv, unsigned* __restrict__ cursor,
                          int* __restrict__ srcs, float* __restrict__ nrm, int E) {
  int e = blockIdx.x * 256 + threadIdx.x;
  if (e >= E) return;
  int s = src[e], d = dst[e];
  unsigned pos = atomicAdd(&cursor[d], 1u);
  srcs[pos] = s;
  nrm[pos] = dinv[s] * dinv[d];
}

// ------------------------------- GEMM: out = A @ W.T (+bias) ----------------

__global__ __launch_bounds__(256, 2) void k_gemm(const float* __restrict__ A,
                                                 const float* __restrict__ W,
                                                 const float* __restrict__ bias,
                                                 float* __restrict__ out, int M) {
  __shared__ float Hs[32][132];   // k-major: Hs[kk][row]
  __shared__ float Ws[32][132];   // k-major: Ws[kk][col]
  const int tid = threadIdx.x;
  const int r0 = blockIdx.x * 128;
  const int tx = tid & 15, ty = tid >> 4;
  const bool full = (r0 + 128 <= M);

  float acc[8][8];
  #pragma unroll
  for (int i = 0; i < 8; i++)
    #pragma unroll
    for (int j = 0; j < 8; j++) acc[i][j] = 0.f;

  #pragma unroll 1
  for (int k0 = 0; k0 < 128; k0 += 32) {
    #pragma unroll
    for (int i = 0; i < 4; i++) {
      int f4 = i * 256 + tid;
      int row = f4 >> 3, kq = f4 & 7;
      int gr = r0 + row;
      float4 v = make_float4(0.f, 0.f, 0.f, 0.f);
      if (full || gr < M) v = *(const float4*)&A[(size_t)gr * 128 + k0 + kq * 4];
      Hs[kq * 4 + 0][row] = v.x; Hs[kq * 4 + 1][row] = v.y;
      Hs[kq * 4 + 2][row] = v.z; Hs[kq * 4 + 3][row] = v.w;
    }
    #pragma unroll
    for (int i = 0; i < 4; i++) {
      int f4 = i * 256 + tid;
      int col = f4 >> 3, kq = f4 & 7;
      float4 v = *(const float4*)&W[(size_t)col * 128 + k0 + kq * 4];
      Ws[kq * 4 + 0][col] = v.x; Ws[kq * 4 + 1][col] = v.y;
      Ws[kq * 4 + 2][col] = v.z; Ws[kq * 4 + 3][col] = v.w;
    }
    __syncthreads();
    #pragma unroll 8
    for (int kk = 0; kk < 32; kk++) {
      float4 a0 = *(const float4*)&Hs[kk][ty * 8];
      float4 a1 = *(const float4*)&Hs[kk][ty * 8 + 4];
      float4 b0 = *(const float4*)&Ws[kk][tx * 8];
      float4 b1 = *(const float4*)&Ws[kk][tx * 8 + 4];
      float a[8] = { a0.x, a0.y, a0.z, a0.w, a1.x, a1.y, a1.z, a1.w };
      float b[8] = { b0.x, b0.y, b0.z, b0.w, b1.x, b1.y, b1.z, b1.w };
      #pragma unroll
      for (int i = 0; i < 8; i++)
        #pragma unroll
        for (int j = 0; j < 8; j++) acc[i][j] += a[i] * b[j];
    }
    __syncthreads();
  }

  float bb[8] = {0.f,0.f,0.f,0.f,0.f,0.f,0.f,0.f};
  if (bias) {
    float4 v0 = *(const float4*)&bias[tx * 8];
    float4 v1 = *(const float4*)&bias[tx * 8 + 4];
    bb[0]=v0.x; bb[1]=v0.y; bb[2]=v0.z; bb[3]=v0.w;
    bb[4]=v1.x; bb[5]=v1.y; bb[6]=v1.z; bb[7]=v1.w;
  }
  #pragma unroll
  for (int i = 0; i < 8; i++) {
    int gr = r0 + ty * 8 + i;
    if (full || gr < M) {
      float4 o0 = make_float4(acc[i][0]+bb[0], acc[i][1]+bb[1], acc[i][2]+bb[2], acc[i][3]+bb[3]);
      float4 o1 = make_float4(acc[i][4]+bb[4], acc[i][5]+bb[5], acc[i][6]+bb[6], acc[i][7]+bb[7]);
      *(float4*)&out[(size_t)gr * 128 + tx * 8] = o0;
      *(float4*)&out[(size_t)gr * 128 + tx * 8 + 4] = o1;
    }
  }
}

// ------------------------------- aggregation -------------------------------

template <bool RELU>
__global__ __launch_bounds__(256) void k_agg(const float* __restrict__ tmp,
                                             const unsigned* __restrict__ rowptr,
                                             const int* __restrict__ srcs,
                                             const float* __restrict__ nrm,
                                             const float* __restrict__ bias,
                                             float* __restrict__ out, int N) {
  int wid = threadIdx.x >> 6, lane = threadIdx.x & 63;
  int n = blockIdx.x * 4 + wid;
  if (n >= N) return;
  unsigned e0 = rowptr[n], e1 = rowptr[n + 1];
  float ax = 0.f, ay = 0.f;
  unsigned e = e0;
  for (; e + 2 <= e1; e += 2) {
    int s0 = srcs[e], s1 = srcs[e + 1];
    float w0 = nrm[e], w1 = nrm[e + 1];
    float2 x0 = *(const float2*)&tmp[(size_t)s0 * 128 + 2 * lane];
    float2 x1 = *(const float2*)&tmp[(size_t)s1 * 128 + 2 * lane];
    ax += w0 * x0.x + w1 * x1.x;
    ay += w0 * x0.y + w1 * x1.y;
  }
  if (e < e1) {
    int s = srcs[e];
    float w = nrm[e];
    float2 x0 = *(const float2*)&tmp[(size_t)s * 128 + 2 * lane];
    ax += w * x0.x;
    ay += w * x0.y;
  }
  float2 bv = *(const float2*)&bias[2 * lane];
  ax += bv.x; ay += bv.y;
  if (RELU) { ax = fmaxf(ax, 0.f); ay = fmaxf(ay, 0.f); }
  float2 o = make_float2(ax, ay);
  *(float2*)&out[(size_t)n * 128 + 2 * lane] = o;
}

// --------------------- SYRK + row/col stats fused --------------------------
// G += h^T h ; colsum += per-col |h| sums ; packed = argmax row-L1 (packed u64)

__global__ __launch_bounds__(256) void k_syrkstats(const float* __restrict__ h,
                                                   float* __restrict__ G,
                                                   float* __restrict__ colsum,
                                                   unsigned long long* __restrict__ packed,
                                                   int N, int rowsPer) {
  __shared__ float hs[8][132];
  __shared__ float csS[128];
  __shared__ unsigned long long pkS[8];
  int tid = threadIdx.x;
  int tx = tid & 15, ty = tid >> 4;
  int rr = tid >> 5, c4 = (tid & 31) * 4;
  float acc[8][8];
  #pragma unroll
  for (int i = 0; i < 8; i++)
    #pragma unroll
    for (int j = 0; j < 8; j++) acc[i][j] = 0.f;
  float ca0 = 0.f, ca1 = 0.f, ca2 = 0.f, ca3 = 0.f;
  unsigned long long best = 0;
  if (tid < 128) csS[tid] = 0.f;
  __syncthreads();

  int rstart = blockIdx.x * rowsPer;
  int rend = rstart + rowsPer;
  if (rend > N) rend = N;
  for (int rb = rstart; rb < rend; rb += 8) {
    int gr = rb + rr;
    float4 v = make_float4(0.f, 0.f, 0.f, 0.f);
    if (gr < rend) v = *(const float4*)&h[(size_t)gr * 128 + c4];
    __syncthreads();
    *(float4*)&hs[rr][c4] = v;
    // row/col stats on the loaded tile
    float avx = fabsf(v.x), avy = fabsf(v.y), avz = fabsf(v.z), avw = fabsf(v.w);
    ca0 += avx; ca1 += avy; ca2 += avz; ca3 += avw;
    float rs = (avx + avy) + (avz + avw);
    rs = dpp_add<0xB1>(rs);
    rs = dpp_add<0x4E>(rs);
    rs = dpp_add<0x124>(rs);
    rs = dpp_add<0x128>(rs);
    rs = dpp_add<0x142>(rs);  // lanes 16-31 / 48-63 hold 32-lane (full-row) sums
    if (gr < rend) {
      unsigned long long pk = ((unsigned long long)__float_as_uint(rs) << 32)
                            | (unsigned long long)(0xFFFFFFFFu - (unsigned)gr);
      if (pk > best) best = pk;
    }
    __syncthreads();
    #pragma unroll
    for (int r2 = 0; r2 < 8; r2++) {
      float4 a0 = *(const float4*)&hs[r2][ty * 8];
      float4 a1 = *(const float4*)&hs[r2][ty * 8 + 4];
      float4 b0 = *(const float4*)&hs[r2][tx * 8];
      float4 b1 = *(const float4*)&hs[r2][tx * 8 + 4];
      float a[8] = { a0.x,a0.y,a0.z,a0.w,a1.x,a1.y,a1.z,a1.w };
      float b[8] = { b0.x,b0.y,b0.z,b0.w,b1.x,b1.y,b1.z,b1.w };
      #pragma unroll
      for (int i = 0; i < 8; i++)
        #pragma unroll
        for (int j = 0; j < 8; j++) acc[i][j] += a[i] * b[j];
    }
  }
  // stats epilogue
  if ((tid & 31) == 16) pkS[tid >> 5] = best;
  atomicAdd(&csS[c4 + 0], ca0);
  atomicAdd(&csS[c4 + 1], ca1);
  atomicAdd(&csS[c4 + 2], ca2);
  atomicAdd(&csS[c4 + 3], ca3);
  __syncthreads();
  if (tid == 0) {
    unsigned long long m = pkS[0];
    #pragma unroll
    for (int w = 1; w < 8; w++) if (pkS[w] > m) m = pkS[w];
    atomicMax(packed, m);
  }
  if (tid < 128) atomicAdd(&colsum[tid], csS[tid]);
  // G epilogue
  #pragma unroll
  for (int i = 0; i < 8; i++)
    #pragma unroll
    for (int j = 0; j < 8; j++)
      atomicAdd(&G[(size_t)(ty * 8 + i) * 128 + tx * 8 + j], acc[i][j]);
}

__global__ void k_extract(const float* __restrict__ h,
                          const unsigned long long* __restrict__ packed,
                          float* __restrict__ hrow, int N) {
  unsigned long long pk = *packed;
  unsigned i = 0xFFFFFFFFu - (unsigned)(pk & 0xFFFFFFFFull);
  if (i >= (unsigned)N) i = 0;
  hrow[threadIdx.x] = h[(size_t)i * 128 + threadIdx.x];
}

// ------------------------------- megastats ---------------------------------
// One block per stat: 2x (tridiag + bisection) trace-sqrt on 128x128 Gram.
// Mapping: thread tid -> row r = tid>>2, slice q = tid&3 (cols 32q..32q+31).
// 2 barriers per Householder step; p-combine via quad_perm DPP; scalar
// reductions via row_ror DPP + 32-float LDS partials summed redundantly.
// colk zero-invariant: colk[c] == 0 for c <= k (diag stashed separately).

__global__ __launch_bounds__(512) void k_megastats(const float* __restrict__ Gall,
                                                   const float* __restrict__ colall,
                                                   const float* __restrict__ hrowall,
                                                   const float* __restrict__ (* /*unused*/) ,
                                                   float* __restrict__ outstats);

__global__ __launch_bounds__(512) void k_megastats2(const float* __restrict__ Gall,
                                                    const float* __restrict__ colall,
                                                    const float* __restrict__ hrowall,
                                                    float* __restrict__ outstats) {
  const int blk = blockIdx.x;
  const float* G = Gall + (size_t)blk * 16384;
  const float* colsum = colall + blk * 128;
  const float* hrowg = hrowall + blk * 128;

  __shared__ __align__(16) float colk[128];
  __shared__ __align__(16) float ww[128];
  __shared__ float diag[128], offd[128];
  __shared__ float asS[128], b2S[128];
  __shared__ float loS[128], hiS[128];
  __shared__ float hiRow[128], gjS[128];
  __shared__ __align__(16) float vpS[32];
  __shared__ __align__(16) float sigS[32];
  __shared__ int cntS[512];
  __shared__ float redw[8];
  __shared__ float scal[16];
  __shared__ int ishared[4];

  const int tid = threadIdx.x;
  const int lane = tid & 63;
  const int wid = tid >> 6;
  const int r = tid >> 2;
  const int q = tid & 3;
  const int cbase = q * 32;
  const int sidx = wid * 4 + (lane >> 4);
  float Areg[32];

  #pragma unroll
  for (int cc = 0; cc < 32; cc++) {
    int c = cbase + cc;
    Areg[cc] = 0.5f * (G[(size_t)r * 128 + c] + G[(size_t)c * 128 + r]);
  }

  for (int solve = 0; solve < 2; solve++) {
    // init: column 0 with zero-invariant + sigma partials
    if (q == 0) colk[r] = (r == 0) ? 0.f : Areg[0];
    if (tid == 0) diag[0] = Areg[0];
    {
      float m2 = (q == 0 && r > 0) ? Areg[0] * Areg[0] : 0.f;
      m2 = dpp_add<0x124>(m2);
      m2 = dpp_add<0x128>(m2);
      if ((lane & 15) == 0) sigS[sidx] = m2;
    }
    __syncthreads();

    for (int k = 0; k <= 125; k++) {
      const int kp1 = k + 1;
      // ---- phase 1: scalars, p = A v, lambda partials ----
      float sig = sum32u(sigS);
      float xk1 = colk[kp1];
      float nx = sqrtf(sig);
      float alpha = (xk1 >= 0.f) ? -nx : nx;
      float vns = 2.0f * (sig - alpha * xk1);
      float rvn = (vns > 1e-35f) ? rsqrtf(vns) : 0.f;
      float vk1 = (xk1 - alpha) * rvn;
      float ckr = colk[r];
      float vr = (r == kp1) ? vk1 : ckr * rvn;  // colk zeros handle r<=k
      const bool act = (cbase + 31 >= k);
      float4 cr[8];
      float p = 0.f, akp1 = 0.f;
      if (act) {
        const float4* cp = (const float4*)&colk[cbase];
        #pragma unroll
        for (int i = 0; i < 8; i++) cr[i] = cp[i];
        if (r >= k) {
          #pragma unroll
          for (int i = 0; i < 8; i++) {
            p += Areg[4*i+0]*cr[i].x + Areg[4*i+1]*cr[i].y
               + Areg[4*i+2]*cr[i].z + Areg[4*i+3]*cr[i].w;
          }
          int kl = kp1 - cbase;
          #pragma unroll
          for (int i = 0; i < 8; i++) {
            if (4*i+0 == kl) akp1 = Areg[4*i+0];
            if (4*i+1 == kl) akp1 = Areg[4*i+1];
            if (4*i+2 == kl) akp1 = Areg[4*i+2];
            if (4*i+3 == kl) akp1 = Areg[4*i+3];
          }
        }
      }
      p = rvn * p - (rvn * alpha) * akp1;
      p = dpp_add<0xB1>(p);
      p = dpp_add<0x4E>(p);     // quad-combined: w at own row
      float wr = p;
      if (q == 0) ww[r] = wr;
      float vp = (q == 0) ? vr * wr : 0.f;
      vp = dpp_add<0x124>(vp);
      vp = dpp_add<0x128>(vp);
      if ((lane & 15) == 0) vpS[sidx] = vp;
      if (tid == 0) offd[k] = alpha;
      __syncthreads();

      // ---- phase 2: rank-2 update, extract col k+1, sigma partials ----
      float lam = sum32u(vpS);
      const int qo = kp1 >> 5;
      float nextc = 0.f;
      if (act && r >= k) {
        float qr = 2.0f * (wr - lam * vr);
        float t2 = 2.0f * lam;
        float arvn = alpha * rvn;
        const float4* wp = (const float4*)&ww[cbase];
        int kl = kp1 - cbase;
        #pragma unroll
        for (int i = 0; i < 8; i++) {
          float4 wc = wp[i];
          {
            float cv = cr[i].x;
            float v = cv * rvn - ((4*i+0 == kl) ? arvn : 0.f);
            float qc = 2.f * wc.x - t2 * v;
            float an = Areg[4*i+0] - (vr * qc + qr * v);
            Areg[4*i+0] = an;
            if (4*i+0 == kl) nextc = an;
          }
          {
            float cv = cr[i].y;
            float v = cv * rvn - ((4*i+1 == kl) ? arvn : 0.f);
            float qc = 2.f * wc.y - t2 * v;
            float an = Areg[4*i+1] - (vr * qc + qr * v);
            Areg[4*i+1] = an;
            if (4*i+1 == kl) nextc = an;
          }
          {
            float cv = cr[i].z;
            float v = cv * rvn - ((4*i+2 == kl) ? arvn : 0.f);
            float qc = 2.f * wc.z - t2 * v;
            float an = Areg[4*i+2] - (vr * qc + qr * v);
            Areg[4*i+2] = an;
            if (4*i+2 == kl) nextc = an;
          }
          {
            float cv = cr[i].w;
            float v = cv * rvn - ((4*i+3 == kl) ? arvn : 0.f);
            float qc = 2.f * wc.w - t2 * v;
            float an = Areg[4*i+3] - (vr * qc + qr * v);
            Areg[4*i+3] = an;
            if (4*i+3 == kl) nextc = an;
          }
        }
      }
      if (q == qo && r >= k) colk[r] = (r <= kp1) ? 0.f : nextc;
      if (q == qo && r == kp1) diag[kp1] = nextc;
      float m2 = (q == qo && r > kp1) ? nextc * nextc : 0.f;
      m2 = dpp_add<0x124>(m2);
      m2 = dpp_add<0x128>(m2);
      if ((lane & 15) == qo) sigS[sidx] = m2;
      __syncthreads();
    }
    if (tid == 0) offd[126] = colk[127];
    if (q == 3 && r == 127) diag[127] = Areg[31];
    __syncthreads();

    // ---- Gershgorin bound ----
    if (tid < 128) {
      float t = fabsf(diag[tid]);
      if (tid > 0) t += fabsf(offd[tid - 1]);
      if (tid < 127) t += fabsf(offd[tid]);
      #pragma unroll
      for (int m = 32; m >= 1; m >>= 1) t = fmaxf(t, __shfl_xor(t, m));
      if (lane == 0) redw[wid] = t;
    }
    __syncthreads();
    if (tid == 0) {
      float g = fmaxf(redw[0], redw[1]);
      if (!(g > 1e-30f)) g = 1.f;
      scal[3] = g; scal[5] = 1.0f / g;
    }
    __syncthreads();
    if (tid < 128) {
      float ginv = scal[5];
      asS[tid] = diag[tid] * ginv;
      float ob = (tid < 127) ? offd[tid] * ginv : 0.f;
      b2S[tid] = ob * ob;
      loS[tid] = -0.0625f;
      hiS[tid] = 1.03125f;
    }
    __syncthreads();

    // ---- multisection bisection (4 probes per eigenvalue per round) ----
    for (int round = 0; round < 12; round++) {
      int kk = tid & 127;
      int t = tid >> 7;
      float l = loS[kk], h = hiS[kk];
      float sigma = l + (h - l) * 0.2f * (float)(t + 1);
      const float PIV = 1e-20f;
      float d = asS[0] - sigma;
      if (fabsf(d) < PIV) d = -PIV;
      int cnt = (d < 0.f) ? 1 : 0;
      for (int i = 1; i < 128; i++) {
        d = (asS[i] - sigma) - b2S[i - 1] * __builtin_amdgcn_rcpf(d);
        if (fabsf(d) < PIV) d = -PIV;
        cnt += (d < 0.f) ? 1 : 0;
      }
      cntS[tid] = cnt;
      __syncthreads();
      if (tid < 128) {
        int c0 = cntS[tid], c1 = cntS[tid + 128], c2 = cntS[tid + 256], c3 = cntS[tid + 384];
        float l2 = loS[tid], h2 = hiS[tid];
        float w = (h2 - l2) * 0.2f;
        int cross = 4;
        if (c0 > tid) cross = 0;
        else if (c1 > tid) cross = 1;
        else if (c2 > tid) cross = 2;
        else if (c3 > tid) cross = 3;
        loS[tid] = (cross == 0) ? l2 : l2 + w * (float)cross;
        hiS[tid] = (cross == 4) ? h2 : l2 + w * (float)(cross + 1);
      }
      __syncthreads();
    }
    // ---- sum sqrt eigenvalues ----
    if (tid < 128) {
      float lam2 = 0.5f * (loS[tid] + hiS[tid]);
      lam2 = fmaxf(lam2, 0.f) * scal[3];
      float s = sqrtf(lam2);
      #pragma unroll
      for (int m = 32; m >= 1; m >>= 1) s += __shfl_xor(s, m);
      if (lane == 0) redw[wid] = s;
    }
    __syncthreads();
    if (tid == 0) scal[4] = redw[0] + redw[1];
    __syncthreads();

    if (solve == 0) {
      // build second matrix G'
      if (tid < 128) hiRow[tid] = hrowg[tid];
      __syncthreads();
      if (tid < 128) {
        float v = colsum[tid];
        int idx = tid;
        #pragma unroll
        for (int m = 32; m >= 1; m >>= 1) {
          float v2 = __shfl_xor(v, m);
          int i2 = __shfl_xor(idx, m);
          if (v2 > v || (v2 == v && i2 < idx)) { v = v2; idx = i2; }
        }
        if (lane == 0) { redw[wid] = v; ishared[wid] = idx; }
        float hv = hiRow[tid];
        float nh = hv * hv;
        #pragma unroll
        for (int m = 32; m >= 1; m >>= 1) nh += __shfl_xor(nh, m);
        if (lane == 0) redw[4 + wid] = nh;
      }
      __syncthreads();
      if (tid == 0) {
        float v0 = redw[0], v1 = redw[1];
        int j = (v1 > v0 || (v1 == v0 && ishared[1] < ishared[0])) ? ishared[1] : ishared[0];
        float nh2 = redw[4] + redw[5];
        float nu = scal[4];
        float Gjj = G[(size_t)j * 128 + j];
        float hij = hiRow[j];
        float sflip = (hij < 0.f) ? -1.f : 1.f;
        scal[6] = 1.0f / (nu * nu);
        scal[7] = sflip / (nu * sqrtf(Gjj) * sqrtf(nh2));
        scal[8] = 1.0f / nh2;
        ishared[2] = j;
      }
      __syncthreads();
      int j = ishared[2];
      if (tid < 128) gjS[tid] = 0.5f * (G[(size_t)tid * 128 + j] + G[(size_t)j * 128 + tid]);
      __syncthreads();
      float inv2 = scal[6], c1 = scal[7], c2 = scal[8];
      float gr_ = gjS[r], hr_ = hiRow[r];
      #pragma unroll
      for (int cc = 0; cc < 32; cc++) {
        int c = cbase + cc;
        float gsym = 0.5f * (G[(size_t)r * 128 + c] + G[(size_t)c * 128 + r]);
        Areg[cc] = gsym * inv2 - c1 * (gr_ * hiRow[c] + hr_ * gjS[c]) + c2 * hr_ * hiRow[c];
      }
      __syncthreads();
    }
  }
  if (tid == 0) outstats[blk] = scal[4];
}

// ------------------------------- host driver -------------------------------

extern "C" void kernel_launch(void* const* d_in, const int* in_sizes, int n_in,
                              void* d_out, int out_size, void* d_ws, size_t ws_size,
                              hipStream_t stream) {
  const float* x = (const float*)d_in[0];
  const int* edge = (const int*)d_in[1];
  const float* encW = (const float*)d_in[2];
  const float* encb = (const float*)d_in[3];
  const float* W0 = (const float*)d_in[4];
  const float* b0 = (const float*)d_in[5];
  const float* W1 = (const float*)d_in[6];
  const float* b1 = (const float*)d_in[7];
  const float* W2 = (const float*)d_in[8];
  const float* b2 = (const float*)d_in[9];

  const int N = in_sizes[0] / 128;
  const int E = in_sizes[1] / 2;
  const int* esrc = edge;
  const int* edst = edge + E;

  float* out = (float*)d_out;
  float* stats_out = out + (size_t)N * 128;

  char* ws = (char*)d_ws;
  size_t offTmp = 0;
  size_t offG = offTmp + (size_t)N * 128 * 4;
  size_t offCol = offG + 4 * 16384 * 4;
  size_t offPkd = offCol + 4 * 128 * 4;
  size_t offHrow = offPkd + 4 * 8;
  size_t offDeg = offHrow + 4 * 128 * 4;
  size_t offRp = offDeg + (size_t)N * 4;
  size_t offCur = offRp + (size_t)(N + 1) * 4;
  size_t offDinv = offCur + (size_t)N * 4;
  size_t offSrc = offDinv + (size_t)N * 4;
  size_t offNrm = offSrc + (size_t)E * 4;
  size_t offPart = offNrm + (size_t)E * 4;
  size_t total = offPart + 256;
  if (ws_size < total) return;

  float* tmp = (float*)(ws + offTmp);
  float* Gall = (float*)(ws + offG);
  float* colall = (float*)(ws + offCol);
  unsigned long long* pkdall = (unsigned long long*)(ws + offPkd);
  float* hrowall = (float*)(ws + offHrow);
  unsigned* deg = (unsigned*)(ws + offDeg);
  unsigned* rowptr = (unsigned*)(ws + offRp);
  unsigned* cursor = (unsigned*)(ws + offCur);
  float* dinv = (float*)(ws + offDinv);
  int* srcs = (int*)(ws + offSrc);
  float* nrm = (float*)(ws + offNrm);
  unsigned* part = (unsigned*)(ws + offPart);

  hipMemsetAsync(ws + offG, 0, 4 * 16384 * 4 + 4 * 128 * 4 + 4 * 8, stream);
  hipMemsetAsync(ws + offDeg, 0, (size_t)N * 4, stream);

  const int EB = (E + 255) / 256;
  const int NB4 = (N + 3) / 4;
  const int GB = (N + 127) / 128;
  const int SB = (N + 1023) / 1024;
  const int syrkRows = (N + 255) / 256;

  k_deg<<<EB, 256, 0, stream>>>(edst, deg, E);
  k_scan1<<<SB, 1024, 0, stream>>>(deg, cursor, part, N);
  k_scan2<<<1, 64, 0, stream>>>(part, SB);
  k_scan3<<<SB, 1024, 0, stream>>>(deg, part, rowptr, cursor, dinv, N, SB);
  k_scatter<<<EB, 256, 0, stream>>>(esrc, edst, dinv, cursor, srcs, nrm, E);

  // encoder: h0 = x @ encW.T + encb  -> d_out
  k_gemm<<<GB, 256, 0, stream>>>(x, encW, encb, out, N);
  k_syrkstats<<<256, 256, 0, stream>>>(out, Gall + 0 * 16384, colall + 0 * 128, pkdall + 0, N, syrkRows);
  k_extract<<<1, 128, 0, stream>>>(out, pkdall + 0, hrowall + 0 * 128, N);

  // layer 0
  k_gemm<<<GB, 256, 0, stream>>>(out, W0, nullptr, tmp, N);
  k_agg<true><<<NB4, 256, 0, stream>>>(tmp, rowptr, srcs, nrm, b0, out, N);
  k_syrkstats<<<256, 256, 0, stream>>>(out, Gall + 1 * 16384, colall + 1 * 128, pkdall + 1, N, syrkRows);
  k_extract<<<1, 128, 0, stream>>>(out, pkdall + 1, hrowall + 1 * 128, N);

  // layer 1
  k_gemm<<<GB, 256, 0, stream>>>(out, W1, nullptr, tmp, N);
  k_agg<true><<<NB4, 256, 0, stream>>>(tmp, rowptr, srcs, nrm, b1, out, N);
  k_syrkstats<<<256, 256, 0, stream>>>(out, Gall + 2 * 16384, colall + 2 * 128, pkdall + 2, N, syrkRows);
  k_extract<<<1, 128, 0, stream>>>(out, pkdall + 2, hrowall + 2 * 128, N);

  // layer 2 (no relu)
  k_gemm<<<GB, 256, 0, stream>>>(out, W2, nullptr, tmp, N);
  k_agg<false><<<NB4, 256, 0, stream>>>(tmp, rowptr, srcs, nrm, b2, out, N);
  k_syrkstats<<<256, 256, 0, stream>>>(out, Gall + 3 * 16384, colall + 3 * 128, pkdall + 3, N, syrkRows);
  k_extract<<<1, 128, 0, stream>>>(out, pkdall + 3, hrowall + 3 * 128, N);

  k_megastats2<<<4, 512, 0, stream>>>(Gall, colall, hrowall, stats_out);
}

// Round 5
// 1912.714 us; speedup vs baseline: 5.9183x; 1.0035x over previous
//
#include <hip/hip_runtime.h>
#include <hip/hip_bf16.h>

// ---------------------------------------------------------------------------
// GCN (3-layer) + encoder + rank_diff stats, all fp32.
// R5: megastats back to q-major (broadcast LDS, no bank conflicts) but with
//     2 barriers/step: lambda partials pre-barrier via full-wave DPP reduce,
//     p combined per-thread from transposed pred[r][q] float4s.
// ---------------------------------------------------------------------------

#define DIM 128

// DPP helpers: 0xB1=quad_perm xor1, 0x4E=quad_perm xor2, 0x124=row_ror:4,
// 0x128=row_ror:8, 0x142=row_bcast15, 0x143=row_bcast31.
template <int CTRL>
__device__ __forceinline__ float dpp_add(float v) {
  int x = __builtin_amdgcn_update_dpp(0, __float_as_int(v), CTRL, 0xF, 0xF, true);
  return v + __int_as_float(x);
}

// full 64-lane sum, result broadcast via readlane(63)
__device__ __forceinline__ float wave_sum(float v) {
  v = dpp_add<0xB1>(v);
  v = dpp_add<0x4E>(v);
  v = dpp_add<0x124>(v);
  v = dpp_add<0x128>(v);   // every lane in each 16-row: 16-sum
  v = dpp_add<0x142>(v);   // lane31: rows0+1, lane63: rows2+3
  v = dpp_add<0x143>(v);   // lane63: total
  return __int_as_float(__builtin_amdgcn_readlane(__float_as_int(v), 63));
}

// ------------------------------- graph setup -------------------------------

__global__ void k_deg(const int* __restrict__ dst, unsigned* __restrict__ deg, int E) {
  int e = blockIdx.x * 256 + threadIdx.x;
  if (e < E) atomicAdd(&deg[dst[e]], 1u);
}

__global__ __launch_bounds__(1024) void k_scan1(const unsigned* __restrict__ deg,
                                                unsigned* __restrict__ loc,
                                                unsigned* __restrict__ part, int n) {
  __shared__ unsigned wtot[16];
  int tid = threadIdx.x, lane = tid & 63, wid = tid >> 6;
  int i = blockIdx.x * 1024 + tid;
  unsigned v = (i < n) ? deg[i] : 0u;
  unsigned s = v;
  #pragma unroll
  for (int d = 1; d < 64; d <<= 1) {
    unsigned t = __shfl_up(s, d);
    if (lane >= d) s += t;
  }
  if (lane == 63) wtot[wid] = s;
  __syncthreads();
  if (tid == 0) {
    unsigned acc = 0;
    #pragma unroll
    for (int w = 0; w < 16; w++) { unsigned t = wtot[w]; wtot[w] = acc; acc += t; }
    part[blockIdx.x] = acc;
  }
  __syncthreads();
  if (i < n) loc[i] = wtot[wid] + (s - v);
}

__global__ void k_scan2(unsigned* part, int nb) {
  int tid = threadIdx.x;  // 64 threads, nb <= 64
  unsigned v = (tid < nb) ? part[tid] : 0u;
  unsigned s = v;
  #pragma unroll
  for (int d = 1; d < 64; d <<= 1) {
    unsigned t = __shfl_up(s, d);
    if (tid >= d) s += t;
  }
  if (tid < nb) part[tid] = s - v;
  if (tid == 63) part[nb] = s;
}

__global__ __launch_bounds__(1024) void k_scan3(const unsigned* __restrict__ deg,
                                                const unsigned* __restrict__ part,
                                                unsigned* __restrict__ rowptr,
                                                unsigned* __restrict__ loc_cursor,
                                                float* __restrict__ dinv, int n, int nb) {
  int i = blockIdx.x * 1024 + threadIdx.x;
  if (i < n) {
    unsigned v = loc_cursor[i] + part[blockIdx.x];
    rowptr[i] = v;
    loc_cursor[i] = v;
    unsigned d = deg[i];
    dinv[i] = d ? 1.0f / sqrtf((float)d) : 0.0f;
  }
  if (i == 0) rowptr[n] = part[nb];
}

__global__ void k_scatter(const int* __restrict__ src, const int* __restrict__ dst,
                          const float* __restrict__ dinv, unsigned* __restrict__ cursor,
                          int* __restrict__ srcs, float* __restrict__ nrm, int E) {
  int e = blockIdx.x * 256 + threadIdx.x;
  if (e >= E) return;
  int s = src[e], d = dst[e];
  unsigned pos = atomicAdd(&cursor[d], 1u);
  srcs[pos] = s;
  nrm[pos] = dinv[s] * dinv[d];
}

// ------------------------------- GEMM: out = A @ W.T (+bias) ----------------

__global__ __launch_bounds__(256, 2) void k_gemm(const float* __restrict__ A,
                                                 const float* __restrict__ W,
                                                 const float* __restrict__ bias,
                                                 float* __restrict__ out, int M) {
  __shared__ float Hs[32][132];   // k-major: Hs[kk][row]
  __shared__ float Ws[32][132];   // k-major: Ws[kk][col]
  const int tid = threadIdx.x;
  const int r0 = blockIdx.x * 128;
  const int tx = tid & 15, ty = tid >> 4;
  const bool full = (r0 + 128 <= M);

  float acc[8][8];
  #pragma unroll
  for (int i = 0; i < 8; i++)
    #pragma unroll
    for (int j = 0; j < 8; j++) acc[i][j] = 0.f;

  #pragma unroll 1
  for (int k0 = 0; k0 < 128; k0 += 32) {
    #pragma unroll
    for (int i = 0; i < 4; i++) {
      int f4 = i * 256 + tid;
      int row = f4 >> 3, kq = f4 & 7;
      int gr = r0 + row;
      float4 v = make_float4(0.f, 0.f, 0.f, 0.f);
      if (full || gr < M) v = *(const float4*)&A[(size_t)gr * 128 + k0 + kq * 4];
      Hs[kq * 4 + 0][row] = v.x; Hs[kq * 4 + 1][row] = v.y;
      Hs[kq * 4 + 2][row] = v.z; Hs[kq * 4 + 3][row] = v.w;
    }
    #pragma unroll
    for (int i = 0; i < 4; i++) {
      int f4 = i * 256 + tid;
      int col = f4 >> 3, kq = f4 & 7;
      float4 v = *(const float4*)&W[(size_t)col * 128 + k0 + kq * 4];
      Ws[kq * 4 + 0][col] = v.x; Ws[kq * 4 + 1][col] = v.y;
      Ws[kq * 4 + 2][col] = v.z; Ws[kq * 4 + 3][col] = v.w;
    }
    __syncthreads();
    #pragma unroll 8
    for (int kk = 0; kk < 32; kk++) {
      float4 a0 = *(const float4*)&Hs[kk][ty * 8];
      float4 a1 = *(const float4*)&Hs[kk][ty * 8 + 4];
      float4 b0 = *(const float4*)&Ws[kk][tx * 8];
      float4 b1 = *(const float4*)&Ws[kk][tx * 8 + 4];
      float a[8] = { a0.x, a0.y, a0.z, a0.w, a1.x, a1.y, a1.z, a1.w };
      float b[8] = { b0.x, b0.y, b0.z, b0.w, b1.x, b1.y, b1.z, b1.w };
      #pragma unroll
      for (int i = 0; i < 8; i++)
        #pragma unroll
        for (int j = 0; j < 8; j++) acc[i][j] += a[i] * b[j];
    }
    __syncthreads();
  }

  float bb[8] = {0.f,0.f,0.f,0.f,0.f,0.f,0.f,0.f};
  if (bias) {
    float4 v0 = *(const float4*)&bias[tx * 8];
    float4 v1 = *(const float4*)&bias[tx * 8 + 4];
    bb[0]=v0.x; bb[1]=v0.y; bb[2]=v0.z; bb[3]=v0.w;
    bb[4]=v1.x; bb[5]=v1.y; bb[6]=v1.z; bb[7]=v1.w;
  }
  #pragma unroll
  for (int i = 0; i < 8; i++) {
    int gr = r0 + ty * 8 + i;
    if (full || gr < M) {
      float4 o0 = make_float4(acc[i][0]+bb[0], acc[i][1]+bb[1], acc[i][2]+bb[2], acc[i][3]+bb[3]);
      float4 o1 = make_float4(acc[i][4]+bb[4], acc[i][5]+bb[5], acc[i][6]+bb[6], acc[i][7]+bb[7]);
      *(float4*)&out[(size_t)gr * 128 + tx * 8] = o0;
      *(float4*)&out[(size_t)gr * 128 + tx * 8 + 4] = o1;
    }
  }
}

// ------------------------------- aggregation -------------------------------

template <bool RELU>
__global__ __launch_bounds__(256) void k_agg(const float* __restrict__ tmp,
                                             const unsigned* __restrict__ rowptr,
                                             const int* __restrict__ srcs,
                                             const float* __restrict__ nrm,
                                             const float* __restrict__ bias,
                                             float* __restrict__ out, int N) {
  int wid = threadIdx.x >> 6, lane = threadIdx.x & 63;
  int n = blockIdx.x * 4 + wid;
  if (n >= N) return;
  unsigned e0 = rowptr[n], e1 = rowptr[n + 1];
  float ax = 0.f, ay = 0.f;
  unsigned e = e0;
  for (; e + 2 <= e1; e += 2) {
    int s0 = srcs[e], s1 = srcs[e + 1];
    float w0 = nrm[e], w1 = nrm[e + 1];
    float2 x0 = *(const float2*)&tmp[(size_t)s0 * 128 + 2 * lane];
    float2 x1 = *(const float2*)&tmp[(size_t)s1 * 128 + 2 * lane];
    ax += w0 * x0.x + w1 * x1.x;
    ay += w0 * x0.y + w1 * x1.y;
  }
  if (e < e1) {
    int s = srcs[e];
    float w = nrm[e];
    float2 x0 = *(const float2*)&tmp[(size_t)s * 128 + 2 * lane];
    ax += w * x0.x;
    ay += w * x0.y;
  }
  float2 bv = *(const float2*)&bias[2 * lane];
  ax += bv.x; ay += bv.y;
  if (RELU) { ax = fmaxf(ax, 0.f); ay = fmaxf(ay, 0.f); }
  float2 o = make_float2(ax, ay);
  *(float2*)&out[(size_t)n * 128 + 2 * lane] = o;
}

// --------------------- SYRK + row/col stats fused --------------------------

__global__ __launch_bounds__(256) void k_syrkstats(const float* __restrict__ h,
                                                   float* __restrict__ G,
                                                   float* __restrict__ colsum,
                                                   unsigned long long* __restrict__ packed,
                                                   int N, int rowsPer) {
  __shared__ float hs[8][132];
  __shared__ float csS[128];
  __shared__ unsigned long long pkS[8];
  int tid = threadIdx.x;
  int tx = tid & 15, ty = tid >> 4;
  int rr = tid >> 5, c4 = (tid & 31) * 4;
  float acc[8][8];
  #pragma unroll
  for (int i = 0; i < 8; i++)
    #pragma unroll
    for (int j = 0; j < 8; j++) acc[i][j] = 0.f;
  float ca0 = 0.f, ca1 = 0.f, ca2 = 0.f, ca3 = 0.f;
  unsigned long long best = 0;
  if (tid < 128) csS[tid] = 0.f;
  __syncthreads();

  int rstart = blockIdx.x * rowsPer;
  int rend = rstart + rowsPer;
  if (rend > N) rend = N;
  for (int rb = rstart; rb < rend; rb += 8) {
    int gr = rb + rr;
    float4 v = make_float4(0.f, 0.f, 0.f, 0.f);
    if (gr < rend) v = *(const float4*)&h[(size_t)gr * 128 + c4];
    __syncthreads();
    *(float4*)&hs[rr][c4] = v;
    float avx = fabsf(v.x), avy = fabsf(v.y), avz = fabsf(v.z), avw = fabsf(v.w);
    ca0 += avx; ca1 += avy; ca2 += avz; ca3 += avw;
    float rs = (avx + avy) + (avz + avw);
    rs = dpp_add<0xB1>(rs);
    rs = dpp_add<0x4E>(rs);
    rs = dpp_add<0x124>(rs);
    rs = dpp_add<0x128>(rs);
    rs = dpp_add<0x142>(rs);  // lanes 16-31 / 48-63 hold full-row sums
    if (gr < rend) {
      unsigned long long pk = ((unsigned long long)__float_as_uint(rs) << 32)
                            | (unsigned long long)(0xFFFFFFFFu - (unsigned)gr);
      if (pk > best) best = pk;
    }
    __syncthreads();
    #pragma unroll
    for (int r2 = 0; r2 < 8; r2++) {
      float4 a0 = *(const float4*)&hs[r2][ty * 8];
      float4 a1 = *(const float4*)&hs[r2][ty * 8 + 4];
      float4 b0 = *(const float4*)&hs[r2][tx * 8];
      float4 b1 = *(const float4*)&hs[r2][tx * 8 + 4];
      float a[8] = { a0.x,a0.y,a0.z,a0.w,a1.x,a1.y,a1.z,a1.w };
      float b[8] = { b0.x,b0.y,b0.z,b0.w,b1.x,b1.y,b1.z,b1.w };
      #pragma unroll
      for (int i = 0; i < 8; i++)
        #pragma unroll
        for (int j = 0; j < 8; j++) acc[i][j] += a[i] * b[j];
    }
  }
  if ((tid & 31) == 16) pkS[tid >> 5] = best;
  atomicAdd(&csS[c4 + 0], ca0);
  atomicAdd(&csS[c4 + 1], ca1);
  atomicAdd(&csS[c4 + 2], ca2);
  atomicAdd(&csS[c4 + 3], ca3);
  __syncthreads();
  if (tid == 0) {
    unsigned long long m = pkS[0];
    #pragma unroll
    for (int w = 1; w < 8; w++) if (pkS[w] > m) m = pkS[w];
    atomicMax(packed, m);
  }
  if (tid < 128) atomicAdd(&colsum[tid], csS[tid]);
  #pragma unroll
  for (int i = 0; i < 8; i++)
    #pragma unroll
    for (int j = 0; j < 8; j++)
      atomicAdd(&G[(size_t)(ty * 8 + i) * 128 + tx * 8 + j], acc[i][j]);
}

__global__ void k_extract(const float* __restrict__ h,
                          const unsigned long long* __restrict__ packed,
                          float* __restrict__ hrow, int N) {
  unsigned long long pk = *packed;
  unsigned i = 0xFFFFFFFFu - (unsigned)(pk & 0xFFFFFFFFull);
  if (i >= (unsigned)N) i = 0;
  hrow[threadIdx.x] = h[(size_t)i * 128 + threadIdx.x];
}

// ------------------------------- megastats ---------------------------------
// One block per stat: 2x (tridiag + bisection) trace-sqrt on 128x128 Gram.
// q-major mapping: q = tid>>7 (wave-pair owns column slice), r = tid&127.
// All per-slice LDS reads are wave-uniform broadcasts (conflict-free).
// 2 barriers/step: lambda (v^T p) partials computed PRE-barrier from each
// thread's own matvec partial via full-wave DPP reduce; p combined per-thread
// post-barrier from transposed pred[r][q] float4s.
// colk zero-invariant: colk[c]==0 for c<=k (diag stashed separately).

__global__ __launch_bounds__(512) void k_megastats3(const float* __restrict__ Gall,
                                                    const float* __restrict__ colall,
                                                    const float* __restrict__ hrowall,
                                                    float* __restrict__ outstats) {
  const int blk = blockIdx.x;
  const float* G = Gall + (size_t)blk * 16384;
  const float* colsum = colall + blk * 128;
  const float* hrowg = hrowall + blk * 128;

  __shared__ __align__(16) float colk[128];
  __shared__ __align__(16) float pred[512];   // [r][q] as float4 rows
  __shared__ __align__(16) float lamp[8];
  __shared__ float sigp[2];
  __shared__ float diag[128], offd[128];
  __shared__ float asS[128], b2S[128];
  __shared__ float loS[128], hiS[128];
  __shared__ float hiRow[128], gjS[128];
  __shared__ int cntS[512];
  __shared__ float redw[8];
  __shared__ float scal[16];
  __shared__ int ishared[4];

  const int tid = threadIdx.x;
  const int lane = tid & 63;
  const int wv = tid >> 6;     // wave 0..7
  const int q = tid >> 7;      // slice 0..3 (wave-pair)
  const int r = tid & 127;     // row
  const int cbase = q * 32;
  float Areg[32];

  // load A = sym(G)
  #pragma unroll
  for (int cc = 0; cc < 32; cc++) {
    int c = cbase + cc;
    Areg[cc] = 0.5f * (G[(size_t)r * 128 + c] + G[(size_t)c * 128 + r]);
  }

  for (int solve = 0; solve < 2; solve++) {
    // init: column 0 (zero-invariant) + diag stash + sigma partials
    if (q == 0) colk[r] = (r == 0) ? 0.f : Areg[0];
    if (tid == 0) diag[0] = Areg[0];
    if (q == 0) {
      float m2 = (r >= 1) ? Areg[0] * Areg[0] : 0.f;
      float s = wave_sum(m2);
      if (lane == 0) sigp[wv] = s;   // wv = 0,1
    }
    __syncthreads();

    for (int k = 0; k <= 125; k++) {
      const int kp1 = k + 1;
      // ---- phase A: scalars, partial p = A v, lambda partials ----
      float sig = sigp[0] + sigp[1];
      float xk1 = colk[kp1];
      float nx = sqrtf(sig);
      float alpha = (xk1 >= 0.f) ? -nx : nx;
      float vns = 2.0f * (sig - alpha * xk1);
      float rvn = (vns > 1e-35f) ? rsqrtf(vns) : 0.f;
      float narvn = -alpha * rvn;
      float ckr = colk[r];
      float vr = ckr * rvn + ((r == kp1) ? narvn : 0.f);
      const bool act = (cbase + 31 >= k);
      float4 cv[8];
      float p = 0.f;
      if (act) {
        const float4* cp = (const float4*)&colk[cbase];  // broadcast reads
        #pragma unroll
        for (int i = 0; i < 8; i++) cv[i] = cp[i];
        if (r >= k) {
          #pragma unroll
          for (int i = 0; i < 8; i++)
            p += Areg[4*i+0]*cv[i].x + Areg[4*i+1]*cv[i].y
               + Areg[4*i+2]*cv[i].z + Areg[4*i+3]*cv[i].w;
          int kl = kp1 - cbase;
          float akp1 = 0.f;
          if (kl >= 0 && kl < 32) {
            #pragma unroll
            for (int i = 0; i < 32; i++) if (i == kl) akp1 = Areg[i];
          }
          p = rvn * p + narvn * akp1;
        }
      }
      pred[r * 4 + q] = p;
      float lp = vr * p;          // vr==0 for r<=k kills garbage rows
      float ls = wave_sum(lp);
      if (lane == 0) lamp[wv] = ls;
      if (tid == 0) offd[k] = alpha;
      __syncthreads();

      // ---- phase B: combine, rank-2 update, extract col k+1, next sigma ----
      float4 l0 = *(const float4*)&lamp[0];
      float4 l1 = *(const float4*)&lamp[4];
      float lam = ((l0.x + l0.y) + (l0.z + l0.w)) + ((l1.x + l1.y) + (l1.z + l1.w));
      float4 pr = *(const float4*)&pred[r * 4];
      float wr = (pr.x + pr.y) + (pr.z + pr.w);
      const int qo = kp1 >> 5;
      float nextc = 0.f;
      if (act && r >= k) {
        float qr = 2.0f * (wr - lam * vr);
        const int kl = kp1 - cbase;
        #pragma unroll
        for (int i = 0; i < 8; i++) {
          const int c0 = 4 * i;
          float4 pA = *(const float4*)&pred[(cbase + c0 + 0) * 4];  // broadcast
          float4 pB = *(const float4*)&pred[(cbase + c0 + 1) * 4];
          float4 pC = *(const float4*)&pred[(cbase + c0 + 2) * 4];
          float4 pD = *(const float4*)&pred[(cbase + c0 + 3) * 4];
          float w0 = (pA.x + pA.y) + (pA.z + pA.w);
          float w1 = (pB.x + pB.y) + (pB.z + pB.w);
          float w2 = (pC.x + pC.y) + (pC.z + pC.w);
          float w3 = (pD.x + pD.y) + (pD.z + pD.w);
          float v0 = cv[i].x * rvn + ((c0 + 0 == kl) ? narvn : 0.f);
          float v1 = cv[i].y * rvn + ((c0 + 1 == kl) ? narvn : 0.f);
          float v2 = cv[i].z * rvn + ((c0 + 2 == kl) ? narvn : 0.f);
          float v3 = cv[i].w * rvn + ((c0 + 3 == kl) ? narvn : 0.f);
          float q0 = 2.f * (w0 - lam * v0);
          float q1 = 2.f * (w1 - lam * v1);
          float q2 = 2.f * (w2 - lam * v2);
          float q3 = 2.f * (w3 - lam * v3);
          float a0 = Areg[c0+0] - (vr * q0 + qr * v0); Areg[c0+0] = a0;
          float a1 = Areg[c0+1] - (vr * q1 + qr * v1); Areg[c0+1] = a1;
          float a2 = Areg[c0+2] - (vr * q2 + qr * v2); Areg[c0+2] = a2;
          float a3 = Areg[c0+3] - (vr * q3 + qr * v3); Areg[c0+3] = a3;
          if (c0 + 0 == kl) nextc = a0;
          if (c0 + 1 == kl) nextc = a1;
          if (c0 + 2 == kl) nextc = a2;
          if (c0 + 3 == kl) nextc = a3;
        }
      }
      if (q == qo && r >= k) colk[r] = (r <= kp1) ? 0.f : nextc;
      if (q == qo && r == kp1) diag[kp1] = nextc;
      if (q == qo) {
        float m2 = (r > kp1 && r >= k) ? nextc * nextc : 0.f;
        float s = wave_sum(m2);
        if (lane == 0) sigp[wv & 1] = s;
      }
      __syncthreads();
    }
    if (tid == 0) offd[126] = colk[127];
    if (q == 3 && r == 127) diag[127] = Areg[31];
    __syncthreads();

    // ---- Gershgorin bound ----
    if (tid < 128) {
      float t = fabsf(diag[tid]);
      if (tid > 0) t += fabsf(offd[tid - 1]);
      if (tid < 127) t += fabsf(offd[tid]);
      #pragma unroll
      for (int m = 32; m >= 1; m >>= 1) t = fmaxf(t, __shfl_xor(t, m));
      if (lane == 0) redw[wv] = t;
    }
    __syncthreads();
    if (tid == 0) {
      float g = fmaxf(redw[0], redw[1]);
      if (!(g > 1e-30f)) g = 1.f;
      scal[3] = g; scal[5] = 1.0f / g;
    }
    __syncthreads();
    if (tid < 128) {
      float ginv = scal[5];
      asS[tid] = diag[tid] * ginv;
      float ob = (tid < 127) ? offd[tid] * ginv : 0.f;
      b2S[tid] = ob * ob;
      loS[tid] = -0.0625f;
      hiS[tid] = 1.03125f;
    }
    __syncthreads();

    // ---- multisection bisection (4 probes per eigenvalue per round) ----
    for (int round = 0; round < 12; round++) {
      int kk = tid & 127;
      int t = tid >> 7;
      float l = loS[kk], h = hiS[kk];
      float sigma = l + (h - l) * 0.2f * (float)(t + 1);
      const float PIV = 1e-20f;
      float d = asS[0] - sigma;
      if (fabsf(d) < PIV) d = -PIV;
      int cnt = (d < 0.f) ? 1 : 0;
      for (int i = 1; i < 128; i++) {
        d = (asS[i] - sigma) - b2S[i - 1] * __builtin_amdgcn_rcpf(d);
        if (fabsf(d) < PIV) d = -PIV;
        cnt += (d < 0.f) ? 1 : 0;
      }
      cntS[tid] = cnt;
      __syncthreads();
      if (tid < 128) {
        int c0 = cntS[tid], c1 = cntS[tid + 128], c2 = cntS[tid + 256], c3 = cntS[tid + 384];
        float l2 = loS[tid], h2 = hiS[tid];
        float w = (h2 - l2) * 0.2f;
        int cross = 4;
        if (c0 > tid) cross = 0;
        else if (c1 > tid) cross = 1;
        else if (c2 > tid) cross = 2;
        else if (c3 > tid) cross = 3;
        loS[tid] = (cross == 0) ? l2 : l2 + w * (float)cross;
        hiS[tid] = (cross == 4) ? h2 : l2 + w * (float)(cross + 1);
      }
      __syncthreads();
    }
    // ---- sum sqrt eigenvalues ----
    if (tid < 128) {
      float lam2 = 0.5f * (loS[tid] + hiS[tid]);
      lam2 = fmaxf(lam2, 0.f) * scal[3];
      float s = sqrtf(lam2);
      #pragma unroll
      for (int m = 32; m >= 1; m >>= 1) s += __shfl_xor(s, m);
      if (lane == 0) redw[wv] = s;
    }
    __syncthreads();
    if (tid == 0) scal[4] = redw[0] + redw[1];
    __syncthreads();

    if (solve == 0) {
      // build second matrix G'
      if (tid < 128) hiRow[tid] = hrowg[tid];
      __syncthreads();
      if (tid < 128) {
        float v = colsum[tid];
        int idx = tid;
        #pragma unroll
        for (int m = 32; m >= 1; m >>= 1) {
          float v2 = __shfl_xor(v, m);
          int i2 = __shfl_xor(idx, m);
          if (v2 > v || (v2 == v && i2 < idx)) { v = v2; idx = i2; }
        }
        if (lane == 0) { redw[wv] = v; ishared[wv] = idx; }
        float hv = hiRow[tid];
        float nh = hv * hv;
        #pragma unroll
        for (int m = 32; m >= 1; m >>= 1) nh += __shfl_xor(nh, m);
        if (lane == 0) redw[4 + wv] = nh;
      }
      __syncthreads();
      if (tid == 0) {
        float v0 = redw[0], v1 = redw[1];
        int j = (v1 > v0 || (v1 == v0 && ishared[1] < ishared[0])) ? ishared[1] : ishared[0];
        float nh2 = redw[4] + redw[5];
        float nu = scal[4];
        float Gjj = G[(size_t)j * 128 + j];
        float hij = hiRow[j];
        float sflip = (hij < 0.f) ? -1.f : 1.f;
        scal[6] = 1.0f / (nu * nu);
        scal[7] = sflip / (nu * sqrtf(Gjj) * sqrtf(nh2));
        scal[8] = 1.0f / nh2;
        ishared[2] = j;
      }
      __syncthreads();
      int j = ishared[2];
      if (tid < 128) gjS[tid] = 0.5f * (G[(size_t)tid * 128 + j] + G[(size_t)j * 128 + tid]);
      __syncthreads();
      float inv2 = scal[6], c1 = scal[7], c2 = scal[8];
      float gr_ = gjS[r], hr_ = hiRow[r];
      #pragma unroll
      for (int cc = 0; cc < 32; cc++) {
        int c = cbase + cc;
        float gsym = 0.5f * (G[(size_t)r * 128 + c] + G[(size_t)c * 128 + r]);
        Areg[cc] = gsym * inv2 - c1 * (gr_ * hiRow[c] + hr_ * gjS[c]) + c2 * hr_ * hiRow[c];
      }
      __syncthreads();
    }
  }
  if (tid == 0) outstats[blk] = scal[4];
}

// ------------------------------- host driver -------------------------------

extern "C" void kernel_launch(void* const* d_in, const int* in_sizes, int n_in,
                              void* d_out, int out_size, void* d_ws, size_t ws_size,
                              hipStream_t stream) {
  const float* x = (const float*)d_in[0];
  const int* edge = (const int*)d_in[1];
  const float* encW = (const float*)d_in[2];
  const float* encb = (const float*)d_in[3];
  const float* W0 = (const float*)d_in[4];
  const float* b0 = (const float*)d_in[5];
  const float* W1 = (const float*)d_in[6];
  const float* b1 = (const float*)d_in[7];
  const float* W2 = (const float*)d_in[8];
  const float* b2 = (const float*)d_in[9];

  const int N = in_sizes[0] / 128;
  const int E = in_sizes[1] / 2;
  const int* esrc = edge;
  const int* edst = edge + E;

  float* out = (float*)d_out;
  float* stats_out = out + (size_t)N * 128;

  char* ws = (char*)d_ws;
  size_t offTmp = 0;
  size_t offG = offTmp + (size_t)N * 128 * 4;
  size_t offCol = offG + 4 * 16384 * 4;
  size_t offPkd = offCol + 4 * 128 * 4;
  size_t offHrow = offPkd + 4 * 8;
  size_t offDeg = offHrow + 4 * 128 * 4;
  size_t offRp = offDeg + (size_t)N * 4;
  size_t offCur = offRp + (size_t)(N + 1) * 4;
  size_t offDinv = offCur + (size_t)N * 4;
  size_t offSrc = offDinv + (size_t)N * 4;
  size_t offNrm = offSrc + (size_t)E * 4;
  size_t offPart = offNrm + (size_t)E * 4;
  size_t total = offPart + 256;
  if (ws_size < total) return;

  float* tmp = (float*)(ws + offTmp);
  float* Gall = (float*)(ws + offG);
  float* colall = (float*)(ws + offCol);
  unsigned long long* pkdall = (unsigned long long*)(ws + offPkd);
  float* hrowall = (float*)(ws + offHrow);
  unsigned* deg = (unsigned*)(ws + offDeg);
  unsigned* rowptr = (unsigned*)(ws + offRp);
  unsigned* cursor = (unsigned*)(ws + offCur);
  float* dinv = (float*)(ws + offDinv);
  int* srcs = (int*)(ws + offSrc);
  float* nrm = (float*)(ws + offNrm);
  unsigned* part = (unsigned*)(ws + offPart);

  hipMemsetAsync(ws + offG, 0, 4 * 16384 * 4 + 4 * 128 * 4 + 4 * 8, stream);
  hipMemsetAsync(ws + offDeg, 0, (size_t)N * 4, stream);

  const int EB = (E + 255) / 256;
  const int NB4 = (N + 3) / 4;
  const int GB = (N + 127) / 128;
  const int SB = (N + 1023) / 1024;
  const int syrkRows = (N + 255) / 256;

  k_deg<<<EB, 256, 0, stream>>>(edst, deg, E);
  k_scan1<<<SB, 1024, 0, stream>>>(deg, cursor, part, N);
  k_scan2<<<1, 64, 0, stream>>>(part, SB);
  k_scan3<<<SB, 1024, 0, stream>>>(deg, part, rowptr, cursor, dinv, N, SB);
  k_scatter<<<EB, 256, 0, stream>>>(esrc, edst, dinv, cursor, srcs, nrm, E);

  // encoder: h0 = x @ encW.T + encb  -> d_out
  k_gemm<<<GB, 256, 0, stream>>>(x, encW, encb, out, N);
  k_syrkstats<<<256, 256, 0, stream>>>(out, Gall + 0 * 16384, colall + 0 * 128, pkdall + 0, N, syrkRows);
  k_extract<<<1, 128, 0, stream>>>(out, pkdall + 0, hrowall + 0 * 128, N);

  // layer 0
  k_gemm<<<GB, 256, 0, stream>>>(out, W0, nullptr, tmp, N);
  k_agg<true><<<NB4, 256, 0, stream>>>(tmp, rowptr, srcs, nrm, b0, out, N);
  k_syrkstats<<<256, 256, 0, stream>>>(out, Gall + 1 * 16384, colall + 1 * 128, pkdall + 1, N, syrkRows);
  k_extract<<<1, 128, 0, stream>>>(out, pkdall + 1, hrowall + 1 * 128, N);

  // layer 1
  k_gemm<<<GB, 256, 0, stream>>>(out, W1, nullptr, tmp, N);
  k_agg<true><<<NB4, 256, 0, stream>>>(tmp, rowptr, srcs, nrm, b1, out, N);
  k_syrkstats<<<256, 256, 0, stream>>>(out, Gall + 2 * 16384, colall + 2 * 128, pkdall + 2, N, syrkRows);
  k_extract<<<1, 128, 0, stream>>>(out, pkdall + 2, hrowall + 2 * 128, N);

  // layer 2 (no relu)
  k_gemm<<<GB, 256, 0, stream>>>(out, W2, nullptr, tmp, N);
  k_agg<false><<<NB4, 256, 0, stream>>>(tmp, rowptr, srcs, nrm, b2, out, N);
  k_syrkstats<<<256, 256, 0, stream>>>(out, Gall + 3 * 16384, colall + 3 * 128, pkdall + 3, N, syrkRows);
  k_extract<<<1, 128, 0, stream>>>(out, pkdall + 3, hrowall + 3 * 128, N);

  k_megastats3<<<4, 512, 0, stream>>>(Gall, colall, hrowall, stats_out);
}

// Round 6
// 1816.113 us; speedup vs baseline: 6.2332x; 1.0532x over previous
//
#include <hip/hip_runtime.h>
#include <hip/hip_bf16.h>

// ---------------------------------------------------------------------------
// GCN (3-layer) + encoder + rank_diff stats, all fp32.
// R6: megastats is LDS-throughput-bound (not barrier-bound). Replace the
//     32-b128 redundant w-combine with ds_add_f32 atomics into ww[2][128]
//     (double-buffered); phase B reads w as 8 broadcast b128. ~320 -> ~150
//     LDS ops/step on the single CU's LDS pipe.
// ---------------------------------------------------------------------------

#define DIM 128

// DPP helpers: 0xB1=quad_perm xor1, 0x4E=quad_perm xor2, 0x124=row_ror:4,
// 0x128=row_ror:8, 0x142=row_bcast15, 0x143=row_bcast31.
template <int CTRL>
__device__ __forceinline__ float dpp_add(float v) {
  int x = __builtin_amdgcn_update_dpp(0, __float_as_int(v), CTRL, 0xF, 0xF, true);
  return v + __int_as_float(x);
}

// full 64-lane sum, result broadcast via readlane(63)
__device__ __forceinline__ float wave_sum(float v) {
  v = dpp_add<0xB1>(v);
  v = dpp_add<0x4E>(v);
  v = dpp_add<0x124>(v);
  v = dpp_add<0x128>(v);
  v = dpp_add<0x142>(v);
  v = dpp_add<0x143>(v);
  return __int_as_float(__builtin_amdgcn_readlane(__float_as_int(v), 63));
}

// ------------------------------- graph setup -------------------------------

__global__ void k_deg(const int* __restrict__ dst, unsigned* __restrict__ deg, int E) {
  int e = blockIdx.x * 256 + threadIdx.x;
  if (e < E) atomicAdd(&deg[dst[e]], 1u);
}

__global__ __launch_bounds__(1024) void k_scan1(const unsigned* __restrict__ deg,
                                                unsigned* __restrict__ loc,
                                                unsigned* __restrict__ part, int n) {
  __shared__ unsigned wtot[16];
  int tid = threadIdx.x, lane = tid & 63, wid = tid >> 6;
  int i = blockIdx.x * 1024 + tid;
  unsigned v = (i < n) ? deg[i] : 0u;
  unsigned s = v;
  #pragma unroll
  for (int d = 1; d < 64; d <<= 1) {
    unsigned t = __shfl_up(s, d);
    if (lane >= d) s += t;
  }
  if (lane == 63) wtot[wid] = s;
  __syncthreads();
  if (tid == 0) {
    unsigned acc = 0;
    #pragma unroll
    for (int w = 0; w < 16; w++) { unsigned t = wtot[w]; wtot[w] = acc; acc += t; }
    part[blockIdx.x] = acc;
  }
  __syncthreads();
  if (i < n) loc[i] = wtot[wid] + (s - v);
}

__global__ void k_scan2(unsigned* part, int nb) {
  int tid = threadIdx.x;  // 64 threads, nb <= 64
  unsigned v = (tid < nb) ? part[tid] : 0u;
  unsigned s = v;
  #pragma unroll
  for (int d = 1; d < 64; d <<= 1) {
    unsigned t = __shfl_up(s, d);
    if (tid >= d) s += t;
  }
  if (tid < nb) part[tid] = s - v;
  if (tid == 63) part[nb] = s;
}

__global__ __launch_bounds__(1024) void k_scan3(const unsigned* __restrict__ deg,
                                                const unsigned* __restrict__ part,
                                                unsigned* __restrict__ rowptr,
                                                unsigned* __restrict__ loc_cursor,
                                                float* __restrict__ dinv, int n, int nb) {
  int i = blockIdx.x * 1024 + threadIdx.x;
  if (i < n) {
    unsigned v = loc_cursor[i] + part[blockIdx.x];
    rowptr[i] = v;
    loc_cursor[i] = v;
    unsigned d = deg[i];
    dinv[i] = d ? 1.0f / sqrtf((float)d) : 0.0f;
  }
  if (i == 0) rowptr[n] = part[nb];
}

__global__ void k_scatter(const int* __restrict__ src, const int* __restrict__ dst,
                          const float* __restrict__ dinv, unsigned* __restrict__ cursor,
                          int* __restrict__ srcs, float* __restrict__ nrm, int E) {
  int e = blockIdx.x * 256 + threadIdx.x;
  if (e >= E) return;
  int s = src[e], d = dst[e];
  unsigned pos = atomicAdd(&cursor[d], 1u);
  srcs[pos] = s;
  nrm[pos] = dinv[s] * dinv[d];
}

// ------------------------------- GEMM: out = A @ W.T (+bias) ----------------

__global__ __launch_bounds__(256, 2) void k_gemm(const float* __restrict__ A,
                                                 const float* __restrict__ W,
                                                 const float* __restrict__ bias,
                                                 float* __restrict__ out, int M) {
  __shared__ float Hs[32][132];   // k-major: Hs[kk][row]
  __shared__ float Ws[32][132];   // k-major: Ws[kk][col]
  const int tid = threadIdx.x;
  const int r0 = blockIdx.x * 128;
  const int tx = tid & 15, ty = tid >> 4;
  const bool full = (r0 + 128 <= M);

  float acc[8][8];
  #pragma unroll
  for (int i = 0; i < 8; i++)
    #pragma unroll
    for (int j = 0; j < 8; j++) acc[i][j] = 0.f;

  #pragma unroll 1
  for (int k0 = 0; k0 < 128; k0 += 32) {
    #pragma unroll
    for (int i = 0; i < 4; i++) {
      int f4 = i * 256 + tid;
      int row = f4 >> 3, kq = f4 & 7;
      int gr = r0 + row;
      float4 v = make_float4(0.f, 0.f, 0.f, 0.f);
      if (full || gr < M) v = *(const float4*)&A[(size_t)gr * 128 + k0 + kq * 4];
      Hs[kq * 4 + 0][row] = v.x; Hs[kq * 4 + 1][row] = v.y;
      Hs[kq * 4 + 2][row] = v.z; Hs[kq * 4 + 3][row] = v.w;
    }
    #pragma unroll
    for (int i = 0; i < 4; i++) {
      int f4 = i * 256 + tid;
      int col = f4 >> 3, kq = f4 & 7;
      float4 v = *(const float4*)&W[(size_t)col * 128 + k0 + kq * 4];
      Ws[kq * 4 + 0][col] = v.x; Ws[kq * 4 + 1][col] = v.y;
      Ws[kq * 4 + 2][col] = v.z; Ws[kq * 4 + 3][col] = v.w;
    }
    __syncthreads();
    #pragma unroll 8
    for (int kk = 0; kk < 32; kk++) {
      float4 a0 = *(const float4*)&Hs[kk][ty * 8];
      float4 a1 = *(const float4*)&Hs[kk][ty * 8 + 4];
      float4 b0 = *(const float4*)&Ws[kk][tx * 8];
      float4 b1 = *(const float4*)&Ws[kk][tx * 8 + 4];
      float a[8] = { a0.x, a0.y, a0.z, a0.w, a1.x, a1.y, a1.z, a1.w };
      float b[8] = { b0.x, b0.y, b0.z, b0.w, b1.x, b1.y, b1.z, b1.w };
      #pragma unroll
      for (int i = 0; i < 8; i++)
        #pragma unroll
        for (int j = 0; j < 8; j++) acc[i][j] += a[i] * b[j];
    }
    __syncthreads();
  }

  float bb[8] = {0.f,0.f,0.f,0.f,0.f,0.f,0.f,0.f};
  if (bias) {
    float4 v0 = *(const float4*)&bias[tx * 8];
    float4 v1 = *(const float4*)&bias[tx * 8 + 4];
    bb[0]=v0.x; bb[1]=v0.y; bb[2]=v0.z; bb[3]=v0.w;
    bb[4]=v1.x; bb[5]=v1.y; bb[6]=v1.z; bb[7]=v1.w;
  }
  #pragma unroll
  for (int i = 0; i < 8; i++) {
    int gr = r0 + ty * 8 + i;
    if (full || gr < M) {
      float4 o0 = make_float4(acc[i][0]+bb[0], acc[i][1]+bb[1], acc[i][2]+bb[2], acc[i][3]+bb[3]);
      float4 o1 = make_float4(acc[i][4]+bb[4], acc[i][5]+bb[5], acc[i][6]+bb[6], acc[i][7]+bb[7]);
      *(float4*)&out[(size_t)gr * 128 + tx * 8] = o0;
      *(float4*)&out[(size_t)gr * 128 + tx * 8 + 4] = o1;
    }
  }
}

// ------------------------------- aggregation -------------------------------

template <bool RELU>
__global__ __launch_bounds__(256) void k_agg(const float* __restrict__ tmp,
                                             const unsigned* __restrict__ rowptr,
                                             const int* __restrict__ srcs,
                                             const float* __restrict__ nrm,
                                             const float* __restrict__ bias,
                                             float* __restrict__ out, int N) {
  int wid = threadIdx.x >> 6, lane = threadIdx.x & 63;
  int n = blockIdx.x * 4 + wid;
  if (n >= N) return;
  unsigned e0 = rowptr[n], e1 = rowptr[n + 1];
  float ax = 0.f, ay = 0.f;
  unsigned e = e0;
  for (; e + 2 <= e1; e += 2) {
    int s0 = srcs[e], s1 = srcs[e + 1];
    float w0 = nrm[e], w1 = nrm[e + 1];
    float2 x0 = *(const float2*)&tmp[(size_t)s0 * 128 + 2 * lane];
    float2 x1 = *(const float2*)&tmp[(size_t)s1 * 128 + 2 * lane];
    ax += w0 * x0.x + w1 * x1.x;
    ay += w0 * x0.y + w1 * x1.y;
  }
  if (e < e1) {
    int s = srcs[e];
    float w = nrm[e];
    float2 x0 = *(const float2*)&tmp[(size_t)s * 128 + 2 * lane];
    ax += w * x0.x;
    ay += w * x0.y;
  }
  float2 bv = *(const float2*)&bias[2 * lane];
  ax += bv.x; ay += bv.y;
  if (RELU) { ax = fmaxf(ax, 0.f); ay = fmaxf(ay, 0.f); }
  float2 o = make_float2(ax, ay);
  *(float2*)&out[(size_t)n * 128 + 2 * lane] = o;
}

// --------------------- SYRK + row/col stats fused --------------------------

__global__ __launch_bounds__(256) void k_syrkstats(const float* __restrict__ h,
                                                   float* __restrict__ G,
                                                   float* __restrict__ colsum,
                                                   unsigned long long* __restrict__ packed,
                                                   int N, int rowsPer) {
  __shared__ float hs[8][132];
  __shared__ float csS[128];
  __shared__ unsigned long long pkS[8];
  int tid = threadIdx.x;
  int tx = tid & 15, ty = tid >> 4;
  int rr = tid >> 5, c4 = (tid & 31) * 4;
  float acc[8][8];
  #pragma unroll
  for (int i = 0; i < 8; i++)
    #pragma unroll
    for (int j = 0; j < 8; j++) acc[i][j] = 0.f;
  float ca0 = 0.f, ca1 = 0.f, ca2 = 0.f, ca3 = 0.f;
  unsigned long long best = 0;
  if (tid < 128) csS[tid] = 0.f;
  __syncthreads();

  int rstart = blockIdx.x * rowsPer;
  int rend = rstart + rowsPer;
  if (rend > N) rend = N;
  for (int rb = rstart; rb < rend; rb += 8) {
    int gr = rb + rr;
    float4 v = make_float4(0.f, 0.f, 0.f, 0.f);
    if (gr < rend) v = *(const float4*)&h[(size_t)gr * 128 + c4];
    __syncthreads();
    *(float4*)&hs[rr][c4] = v;
    float avx = fabsf(v.x), avy = fabsf(v.y), avz = fabsf(v.z), avw = fabsf(v.w);
    ca0 += avx; ca1 += avy; ca2 += avz; ca3 += avw;
    float rs = (avx + avy) + (avz + avw);
    rs = dpp_add<0xB1>(rs);
    rs = dpp_add<0x4E>(rs);
    rs = dpp_add<0x124>(rs);
    rs = dpp_add<0x128>(rs);
    rs = dpp_add<0x142>(rs);  // lanes 16-31 / 48-63 hold full-row sums
    if (gr < rend) {
      unsigned long long pk = ((unsigned long long)__float_as_uint(rs) << 32)
                            | (unsigned long long)(0xFFFFFFFFu - (unsigned)gr);
      if (pk > best) best = pk;
    }
    __syncthreads();
    #pragma unroll
    for (int r2 = 0; r2 < 8; r2++) {
      float4 a0 = *(const float4*)&hs[r2][ty * 8];
      float4 a1 = *(const float4*)&hs[r2][ty * 8 + 4];
      float4 b0 = *(const float4*)&hs[r2][tx * 8];
      float4 b1 = *(const float4*)&hs[r2][tx * 8 + 4];
      float a[8] = { a0.x,a0.y,a0.z,a0.w,a1.x,a1.y,a1.z,a1.w };
      float b[8] = { b0.x,b0.y,b0.z,b0.w,b1.x,b1.y,b1.z,b1.w };
      #pragma unroll
      for (int i = 0; i < 8; i++)
        #pragma unroll
        for (int j = 0; j < 8; j++) acc[i][j] += a[i] * b[j];
    }
  }
  if ((tid & 31) == 16) pkS[tid >> 5] = best;
  atomicAdd(&csS[c4 + 0], ca0);
  atomicAdd(&csS[c4 + 1], ca1);
  atomicAdd(&csS[c4 + 2], ca2);
  atomicAdd(&csS[c4 + 3], ca3);
  __syncthreads();
  if (tid == 0) {
    unsigned long long m = pkS[0];
    #pragma unroll
    for (int w = 1; w < 8; w++) if (pkS[w] > m) m = pkS[w];
    atomicMax(packed, m);
  }
  if (tid < 128) atomicAdd(&colsum[tid], csS[tid]);
  #pragma unroll
  for (int i = 0; i < 8; i++)
    #pragma unroll
    for (int j = 0; j < 8; j++)
      atomicAdd(&G[(size_t)(ty * 8 + i) * 128 + tx * 8 + j], acc[i][j]);
}

__global__ void k_extract(const float* __restrict__ h,
                          const unsigned long long* __restrict__ packed,
                          float* __restrict__ hrow, int N) {
  unsigned long long pk = *packed;
  unsigned i = 0xFFFFFFFFu - (unsigned)(pk & 0xFFFFFFFFull);
  if (i >= (unsigned)N) i = 0;
  hrow[threadIdx.x] = h[(size_t)i * 128 + threadIdx.x];
}

// ------------------------------- megastats ---------------------------------
// One block per stat: 2x (tridiag + bisection) trace-sqrt on 128x128 Gram.
// q-major mapping: q = tid>>7 (wave-pair owns 32-col slice), r = tid&127.
// All slice LDS reads are wave-uniform broadcasts. 2 barriers/step.
// w-combine via ds_add_f32 atomics into double-buffered ww[2][128]:
// phase A adds matvec partials (cross-wave combine in LDS banks);
// phase B reads combined w as 8 broadcast b128. lambda via in-register
// DPP wave_sum of v_r*p partials (pre-barrier).
// colk zero-invariant: colk[c]==0 for c<=k (diag stashed separately).

__global__ __launch_bounds__(512) void k_megastats4(const float* __restrict__ Gall,
                                                    const float* __restrict__ colall,
                                                    const float* __restrict__ hrowall,
                                                    float* __restrict__ outstats) {
  const int blk = blockIdx.x;
  const float* G = Gall + (size_t)blk * 16384;
  const float* colsum = colall + blk * 128;
  const float* hrowg = hrowall + blk * 128;

  __shared__ __align__(16) float colk[128];
  __shared__ __align__(16) float wwF[256];    // ww[2][128] double buffer
  __shared__ __align__(16) float lamp[8];
  __shared__ float sigp[2];
  __shared__ float diag[128], offd[128];
  __shared__ float asS[128], b2S[128];
  __shared__ float loS[128], hiS[128];
  __shared__ float hiRow[128], gjS[128];
  __shared__ int cntS[512];
  __shared__ float redw[8];
  __shared__ float scal[16];
  __shared__ int ishared[4];

  const int tid = threadIdx.x;
  const int lane = tid & 63;
  const int wv = tid >> 6;     // wave 0..7
  const int q = tid >> 7;      // slice 0..3 (wave-pair)
  const int r = tid & 127;     // row
  const int cbase = q * 32;
  float Areg[32];

  // load A = sym(G)
  #pragma unroll
  for (int cc = 0; cc < 32; cc++) {
    int c = cbase + cc;
    Areg[cc] = 0.5f * (G[(size_t)r * 128 + c] + G[(size_t)c * 128 + r]);
  }

  for (int solve = 0; solve < 2; solve++) {
    // init: column 0 (zero-invariant) + diag stash + sigma partials + ww zero
    if (q == 0) colk[r] = (r == 0) ? 0.f : Areg[0];
    if (tid == 0) diag[0] = Areg[0];
    if (tid < 256) wwF[tid] = 0.f;
    if (q == 0) {
      float m2 = (r >= 1) ? Areg[0] * Areg[0] : 0.f;
      float s = wave_sum(m2);
      if (lane == 0) sigp[wv] = s;   // wv = 0,1
    }
    __syncthreads();

    for (int k = 0; k <= 125; k++) {
      const int kp1 = k + 1;
      float* wwc = &wwF[(k & 1) * 128];
      float* wwn = &wwF[(1 - (k & 1)) * 128];
      // ---- phase A: scalars, partial p = A v -> ds_add, lambda partials ----
      float sig = sigp[0] + sigp[1];
      float xk1 = colk[kp1];
      float nx = sqrtf(sig);
      float alpha = (xk1 >= 0.f) ? -nx : nx;
      float vns = 2.0f * (sig - alpha * xk1);
      float rvn = (vns > 1e-35f) ? rsqrtf(vns) : 0.f;
      float narvn = -alpha * rvn;
      float ckr = colk[r];
      float vr = ckr * rvn + ((r == kp1) ? narvn : 0.f);
      const bool act = (cbase + 31 >= k);
      float4 cv[8];
      float p = 0.f;
      if (act) {
        const float4* cp = (const float4*)&colk[cbase];  // broadcast reads
        #pragma unroll
        for (int i = 0; i < 8; i++) cv[i] = cp[i];
        if (r >= k) {
          #pragma unroll
          for (int i = 0; i < 8; i++)
            p += Areg[4*i+0]*cv[i].x + Areg[4*i+1]*cv[i].y
               + Areg[4*i+2]*cv[i].z + Areg[4*i+3]*cv[i].w;
          int kl = kp1 - cbase;
          float akp1 = 0.f;
          if (kl >= 0 && kl < 32) {
            #pragma unroll
            for (int i = 0; i < 32; i++) if (i == kl) akp1 = Areg[i];
          }
          p = rvn * p + narvn * akp1;
          atomicAdd(&wwc[r], p);      // ds_add_f32, cross-wave combine
        }
      }
      float lp = vr * p;              // p==0 for skipped threads
      float ls = wave_sum(lp);
      if (lane == 0) lamp[wv] = ls;
      if (tid == 0) offd[k] = alpha;
      __syncthreads();

      // ---- phase B: rank-2 update, extract col k+1, next sigma, zero wwn ----
      float4 l0 = *(const float4*)&lamp[0];
      float4 l1 = *(const float4*)&lamp[4];
      float lam = ((l0.x + l0.y) + (l0.z + l0.w)) + ((l1.x + l1.y) + (l1.z + l1.w));
      const int qo = kp1 >> 5;
      float nextc = 0.f;
      if (act && r >= k) {
        float wr = wwc[r];
        float qr = 2.0f * (wr - lam * vr);
        const int kl = kp1 - cbase;
        const float4* wp = (const float4*)&wwc[cbase];   // broadcast reads
        #pragma unroll
        for (int i = 0; i < 8; i++) {
          const int c0 = 4 * i;
          float4 wc = wp[i];
          float v0 = cv[i].x * rvn + ((c0 + 0 == kl) ? narvn : 0.f);
          float v1 = cv[i].y * rvn + ((c0 + 1 == kl) ? narvn : 0.f);
          float v2 = cv[i].z * rvn + ((c0 + 2 == kl) ? narvn : 0.f);
          float v3 = cv[i].w * rvn + ((c0 + 3 == kl) ? narvn : 0.f);
          float q0 = 2.f * (wc.x - lam * v0);
          float q1 = 2.f * (wc.y - lam * v1);
          float q2 = 2.f * (wc.z - lam * v2);
          float q3 = 2.f * (wc.w - lam * v3);
          float a0 = Areg[c0+0] - (vr * q0 + qr * v0); Areg[c0+0] = a0;
          float a1 = Areg[c0+1] - (vr * q1 + qr * v1); Areg[c0+1] = a1;
          float a2 = Areg[c0+2] - (vr * q2 + qr * v2); Areg[c0+2] = a2;
          float a3 = Areg[c0+3] - (vr * q3 + qr * v3); Areg[c0+3] = a3;
          if (c0 + 0 == kl) nextc = a0;
          if (c0 + 1 == kl) nextc = a1;
          if (c0 + 2 == kl) nextc = a2;
          if (c0 + 3 == kl) nextc = a3;
        }
      }
      if (q == qo && r >= k) colk[r] = (r <= kp1) ? 0.f : nextc;
      if (q == qo && r == kp1) diag[kp1] = nextc;
      if (q == qo) {
        float m2 = (r > kp1 && r >= k) ? nextc * nextc : 0.f;
        float s = wave_sum(m2);
        if (lane == 0) sigp[wv & 1] = s;
      }
      if (q == 1) wwn[r] = 0.f;   // zero next buffer (read last in step k-1)
      __syncthreads();
    }
    if (tid == 0) offd[126] = colk[127];
    if (q == 3 && r == 127) diag[127] = Areg[31];
    __syncthreads();

    // ---- Gershgorin bound ----
    if (tid < 128) {
      float t = fabsf(diag[tid]);
      if (tid > 0) t += fabsf(offd[tid - 1]);
      if (tid < 127) t += fabsf(offd[tid]);
      #pragma unroll
      for (int m = 32; m >= 1; m >>= 1) t = fmaxf(t, __shfl_xor(t, m));
      if (lane == 0) redw[wv] = t;
    }
    __syncthreads();
    if (tid == 0) {
      float g = fmaxf(redw[0], redw[1]);
      if (!(g > 1e-30f)) g = 1.f;
      scal[3] = g; scal[5] = 1.0f / g;
    }
    __syncthreads();
    if (tid < 128) {
      float ginv = scal[5];
      asS[tid] = diag[tid] * ginv;
      float ob = (tid < 127) ? offd[tid] * ginv : 0.f;
      b2S[tid] = ob * ob;
      loS[tid] = -0.0625f;
      hiS[tid] = 1.03125f;
    }
    __syncthreads();

    // ---- multisection bisection (4 probes per eigenvalue per round) ----
    for (int round = 0; round < 12; round++) {
      int kk = tid & 127;
      int t = tid >> 7;
      float l = loS[kk], h = hiS[kk];
      float sigma = l + (h - l) * 0.2f * (float)(t + 1);
      const float PIV = 1e-20f;
      float d = asS[0] - sigma;
      if (fabsf(d) < PIV) d = -PIV;
      int cnt = (d < 0.f) ? 1 : 0;
      for (int i = 1; i < 128; i++) {
        d = (asS[i] - sigma) - b2S[i - 1] * __builtin_amdgcn_rcpf(d);
        if (fabsf(d) < PIV) d = -PIV;
        cnt += (d < 0.f) ? 1 : 0;
      }
      cntS[tid] = cnt;
      __syncthreads();
      if (tid < 128) {
        int c0 = cntS[tid], c1 = cntS[tid + 128], c2 = cntS[tid + 256], c3 = cntS[tid + 384];
        float l2 = loS[tid], h2 = hiS[tid];
        float w = (h2 - l2) * 0.2f;
        int cross = 4;
        if (c0 > tid) cross = 0;
        else if (c1 > tid) cross = 1;
        else if (c2 > tid) cross = 2;
        else if (c3 > tid) cross = 3;
        loS[tid] = (cross == 0) ? l2 : l2 + w * (float)cross;
        hiS[tid] = (cross == 4) ? h2 : l2 + w * (float)(cross + 1);
      }
      __syncthreads();
    }
    // ---- sum sqrt eigenvalues ----
    if (tid < 128) {
      float lam2 = 0.5f * (loS[tid] + hiS[tid]);
      lam2 = fmaxf(lam2, 0.f) * scal[3];
      float s = sqrtf(lam2);
      #pragma unroll
      for (int m = 32; m >= 1; m >>= 1) s += __shfl_xor(s, m);
      if (lane == 0) redw[wv] = s;
    }
    __syncthreads();
    if (tid == 0) scal[4] = redw[0] + redw[1];
    __syncthreads();

    if (solve == 0) {
      // build second matrix G'
      if (tid < 128) hiRow[tid] = hrowg[tid];
      __syncthreads();
      if (tid < 128) {
        float v = colsum[tid];
        int idx = tid;
        #pragma unroll
        for (int m = 32; m >= 1; m >>= 1) {
          float v2 = __shfl_xor(v, m);
          int i2 = __shfl_xor(idx, m);
          if (v2 > v || (v2 == v && i2 < idx)) { v = v2; idx = i2; }
        }
        if (lane == 0) { redw[wv] = v; ishared[wv] = idx; }
        float hv = hiRow[tid];
        float nh = hv * hv;
        #pragma unroll
        for (int m = 32; m >= 1; m >>= 1) nh += __shfl_xor(nh, m);
        if (lane == 0) redw[4 + wv] = nh;
      }
      __syncthreads();
      if (tid == 0) {
        float v0 = redw[0], v1 = redw[1];
        int j = (v1 > v0 || (v1 == v0 && ishared[1] < ishared[0])) ? ishared[1] : ishared[0];
        float nh2 = redw[4] + redw[5];
        float nu = scal[4];
        float Gjj = G[(size_t)j * 128 + j];
        float hij = hiRow[j];
        float sflip = (hij < 0.f) ? -1.f : 1.f;
        scal[6] = 1.0f / (nu * nu);
        scal[7] = sflip / (nu * sqrtf(Gjj) * sqrtf(nh2));
        scal[8] = 1.0f / nh2;
        ishared[2] = j;
      }
      __syncthreads();
      int j = ishared[2];
      if (tid < 128) gjS[tid] = 0.5f * (G[(size_t)tid * 128 + j] + G[(size_t)j * 128 + tid]);
      __syncthreads();
      float inv2 = scal[6], c1 = scal[7], c2 = scal[8];
      float gr_ = gjS[r], hr_ = hiRow[r];
      #pragma unroll
      for (int cc = 0; cc < 32; cc++) {
        int c = cbase + cc;
        float gsym = 0.5f * (G[(size_t)r * 128 + c] + G[(size_t)c * 128 + r]);
        Areg[cc] = gsym * inv2 - c1 * (gr_ * hiRow[c] + hr_ * gjS[c]) + c2 * hr_ * hiRow[c];
      }
      __syncthreads();
    }
  }
  if (tid == 0) outstats[blk] = scal[4];
}

// ------------------------------- host driver -------------------------------

extern "C" void kernel_launch(void* const* d_in, const int* in_sizes, int n_in,
                              void* d_out, int out_size, void* d_ws, size_t ws_size,
                              hipStream_t stream) {
  const float* x = (const float*)d_in[0];
  const int* edge = (const int*)d_in[1];
  const float* encW = (const float*)d_in[2];
  const float* encb = (const float*)d_in[3];
  const float* W0 = (const float*)d_in[4];
  const float* b0 = (const float*)d_in[5];
  const float* W1 = (const float*)d_in[6];
  const float* b1 = (const float*)d_in[7];
  const float* W2 = (const float*)d_in[8];
  const float* b2 = (const float*)d_in[9];

  const int N = in_sizes[0] / 128;
  const int E = in_sizes[1] / 2;
  const int* esrc = edge;
  const int* edst = edge + E;

  float* out = (float*)d_out;
  float* stats_out = out + (size_t)N * 128;

  char* ws = (char*)d_ws;
  size_t offTmp = 0;
  size_t offG = offTmp + (size_t)N * 128 * 4;
  size_t offCol = offG + 4 * 16384 * 4;
  size_t offPkd = offCol + 4 * 128 * 4;
  size_t offHrow = offPkd + 4 * 8;
  size_t offDeg = offHrow + 4 * 128 * 4;
  size_t offRp = offDeg + (size_t)N * 4;
  size_t offCur = offRp + (size_t)(N + 1) * 4;
  size_t offDinv = offCur + (size_t)N * 4;
  size_t offSrc = offDinv + (size_t)N * 4;
  size_t offNrm = offSrc + (size_t)E * 4;
  size_t offPart = offNrm + (size_t)E * 4;
  size_t total = offPart + 256;
  if (ws_size < total) return;

  float* tmp = (float*)(ws + offTmp);
  float* Gall = (float*)(ws + offG);
  float* colall = (float*)(ws + offCol);
  unsigned long long* pkdall = (unsigned long long*)(ws + offPkd);
  float* hrowall = (float*)(ws + offHrow);
  unsigned* deg = (unsigned*)(ws + offDeg);
  unsigned* rowptr = (unsigned*)(ws + offRp);
  unsigned* cursor = (unsigned*)(ws + offCur);
  float* dinv = (float*)(ws + offDinv);
  int* srcs = (int*)(ws + offSrc);
  float* nrm = (float*)(ws + offNrm);
  unsigned* part = (unsigned*)(ws + offPart);

  hipMemsetAsync(ws + offG, 0, 4 * 16384 * 4 + 4 * 128 * 4 + 4 * 8, stream);
  hipMemsetAsync(ws + offDeg, 0, (size_t)N * 4, stream);

  const int EB = (E + 255) / 256;
  const int NB4 = (N + 3) / 4;
  const int GB = (N + 127) / 128;
  const int SB = (N + 1023) / 1024;
  const int syrkRows = (N + 255) / 256;

  k_deg<<<EB, 256, 0, stream>>>(edst, deg, E);
  k_scan1<<<SB, 1024, 0, stream>>>(deg, cursor, part, N);
  k_scan2<<<1, 64, 0, stream>>>(part, SB);
  k_scan3<<<SB, 1024, 0, stream>>>(deg, part, rowptr, cursor, dinv, N, SB);
  k_scatter<<<EB, 256, 0, stream>>>(esrc, edst, dinv, cursor, srcs, nrm, E);

  // encoder: h0 = x @ encW.T + encb  -> d_out
  k_gemm<<<GB, 256, 0, stream>>>(x, encW, encb, out, N);
  k_syrkstats<<<256, 256, 0, stream>>>(out, Gall + 0 * 16384, colall + 0 * 128, pkdall + 0, N, syrkRows);
  k_extract<<<1, 128, 0, stream>>>(out, pkdall + 0, hrowall + 0 * 128, N);

  // layer 0
  k_gemm<<<GB, 256, 0, stream>>>(out, W0, nullptr, tmp, N);
  k_agg<true><<<NB4, 256, 0, stream>>>(tmp, rowptr, srcs, nrm, b0, out, N);
  k_syrkstats<<<256, 256, 0, stream>>>(out, Gall + 1 * 16384, colall + 1 * 128, pkdall + 1, N, syrkRows);
  k_extract<<<1, 128, 0, stream>>>(out, pkdall + 1, hrowall + 1 * 128, N);

  // layer 1
  k_gemm<<<GB, 256, 0, stream>>>(out, W1, nullptr, tmp, N);
  k_agg<true><<<NB4, 256, 0, stream>>>(tmp, rowptr, srcs, nrm, b1, out, N);
  k_syrkstats<<<256, 256, 0, stream>>>(out, Gall + 2 * 16384, colall + 2 * 128, pkdall + 2, N, syrkRows);
  k_extract<<<1, 128, 0, stream>>>(out, pkdall + 2, hrowall + 2 * 128, N);

  // layer 2 (no relu)
  k_gemm<<<GB, 256, 0, stream>>>(out, W2, nullptr, tmp, N);
  k_agg<false><<<NB4, 256, 0, stream>>>(tmp, rowptr, srcs, nrm, b2, out, N);
  k_syrkstats<<<256, 256, 0, stream>>>(out, Gall + 3 * 16384, colall + 3 * 128, pkdall + 3, N, syrkRows);
  k_extract<<<1, 128, 0, stream>>>(out, pkdall + 3, hrowall + 3 * 128, N);

  k_megastats4<<<4, 512, 0, stream>>>(Gall, colall, hrowall, stats_out);
}